// Round 1
// baseline (1401.230 us; speedup 1.0000x reference)
//
#include <hip/hip_runtime.h>
#include <cstdint>
#include <cstddef>

#define NN 50000
#define EE 800000
// D=64, HEADS=4, C=16, 2D=128

// ---------- K1: xl = x@Wl, xr = x@Wr ----------
__global__ __launch_bounds__(256) void k_node_linear(
    const float* __restrict__ x, const float* __restrict__ Wl,
    const float* __restrict__ Wr, float* __restrict__ xl,
    float* __restrict__ xr, int n) {
  __shared__ float sWl[64 * 64];
  __shared__ float sWr[64 * 64];
  __shared__ float sx[4][64];
  int tid = threadIdx.x;
  for (int i = tid; i < 4096; i += 256) { sWl[i] = Wl[i]; sWr[i] = Wr[i]; }
  __syncthreads();
  int y = tid >> 6, t = tid & 63;
  for (int base = blockIdx.x * 4; base < n; base += gridDim.x * 4) {
    int i = base + y;
    if (i >= n) continue;            // wave-uniform (y uniform per wave)
    sx[y][t] = x[(size_t)i * 64 + t];  // wave-local LDS, no block sync needed
    float accl = 0.f, accr = 0.f;
#pragma unroll 16
    for (int k = 0; k < 64; k++) {
      float xv = sx[y][k];
      accl += xv * sWl[k * 64 + t];
      accr += xv * sWr[k * 64 + t];
    }
    xl[(size_t)i * 64 + t] = accl;
    xr[(size_t)i * 64 + t] = accr;
  }
}

// ---------- K2: logits[e,h] = sum_c leakyrelu(xl[s]+xr[d]+ea@We)*att ; counts ----------
__global__ __launch_bounds__(256) void k_edge_logits(
    const float* __restrict__ ea, const int* __restrict__ ei,
    const float* __restrict__ We, const float* __restrict__ att,
    const float* __restrict__ xl, const float* __restrict__ xr,
    float* __restrict__ logits, int* __restrict__ counts, int ne) {
  __shared__ float sWe[64 * 64];
  __shared__ float sea[4][64];
  int tid = threadIdx.x;
  for (int i = tid; i < 4096; i += 256) sWe[i] = We[i];
  __syncthreads();
  int y = tid >> 6, t = tid & 63;
  int h = t >> 4;
  float attv = att[t];  // att[h*16+c] with t = h*16+c
  for (int base = blockIdx.x * 4; base < ne; base += gridDim.x * 4) {
    int e = base + y;
    if (e >= ne) continue;  // wave-uniform
    int s = ei[e], d = ei[EE + e];
    sea[y][t] = ea[(size_t)e * 64 + t];  // wave-local
    float ef = 0.f;
#pragma unroll 16
    for (int k = 0; k < 64; k++) ef += sea[y][k] * sWe[k * 64 + t];
    float z = ef + xl[(size_t)s * 64 + t] + xr[(size_t)d * 64 + t];
    z = (z >= 0.f) ? z : 0.2f * z;
    float v = z * attv;
#pragma unroll
    for (int m = 1; m < 16; m <<= 1) v += __shfl_xor(v, m, 64);
    if ((t & 15) == 0) logits[(size_t)e * 4 + h] = v;
    if (t == 0) atomicAdd(&counts[d], 1);
  }
}

// ---------- K3: exclusive scan of counts -> offsets, cursor ----------
__global__ __launch_bounds__(1024) void k_scan(const int* __restrict__ counts,
                                               int* __restrict__ offsets,
                                               int* __restrict__ cursor, int n) {
  __shared__ int tmp[1024];
  __shared__ int carry;
  int tid = threadIdx.x;
  if (tid == 0) carry = 0;
  __syncthreads();
  for (int base = 0; base < n; base += 1024) {
    int idx = base + tid;
    int v = (idx < n) ? counts[idx] : 0;
    tmp[tid] = v;
    __syncthreads();
    for (int off = 1; off < 1024; off <<= 1) {
      int tval = (tid >= off) ? tmp[tid - off] : 0;
      __syncthreads();
      tmp[tid] += tval;
      __syncthreads();
    }
    int excl = carry + tmp[tid] - v;
    if (idx < n) { offsets[idx] = excl; cursor[idx] = excl; }
    __syncthreads();
    if (tid == 1023) carry += tmp[1023];
    __syncthreads();
  }
  if (tid == 0) offsets[n] = carry;
}

// ---------- K4: scatter edge ids into CSR ----------
__global__ __launch_bounds__(256) void k_scatter(const int* __restrict__ ei,
                                                 int* __restrict__ cursor,
                                                 int* __restrict__ edge_of, int ne) {
  int e = blockIdx.x * blockDim.x + threadIdx.x;
  for (; e < ne; e += gridDim.x * blockDim.x) {
    int d = ei[EE + e];
    int pos = atomicAdd(&cursor[d], 1);
    edge_of[pos] = e;
  }
}

// ---------- K5: per-node segment softmax + aggregate ----------
__global__ __launch_bounds__(256) void k_node_agg(
    const int* __restrict__ ei, const int* __restrict__ offsets,
    const int* __restrict__ edge_of, const float* __restrict__ logits,
    const float* __restrict__ xl, const float* __restrict__ bias,
    float* __restrict__ xout, int n) {
  int tid = threadIdx.x;
  int y = tid >> 6, t = tid & 63;
  int h = t >> 4;
  float bv = bias[t];
  for (int base = blockIdx.x * 4; base < n; base += gridDim.x * 4) {
    int i = base + y;
    if (i >= n) continue;  // wave-uniform
    int beg = offsets[i], end = offsets[i + 1];
    float m = -__builtin_inff();
    for (int j = beg; j < end; j++) {
      int e = edge_of[j];
      m = fmaxf(m, logits[(size_t)e * 4 + h]);
    }
    float acc = 0.f, den = 0.f;
    for (int j = beg; j < end; j++) {
      int e = edge_of[j];
      int s = ei[e];
      float p = __expf(logits[(size_t)e * 4 + h] - m);
      den += p;
      acc += p * xl[(size_t)s * 64 + t];
    }
    xout[(size_t)i * 64 + t] = acc / (den + 1e-16f) + bv;
  }
}

// ---------- K6: edge MLP: LN(concat) -> ReLU -> @Wm + bm + residual ----------
__global__ __launch_bounds__(256) void k_edge_mlp(
    const float* __restrict__ ea, const int* __restrict__ ei,
    const float* __restrict__ xout, const float* __restrict__ lng,
    const float* __restrict__ lnb, const float* __restrict__ Wm,
    const float* __restrict__ bm, float* __restrict__ eout, int ne) {
  __shared__ float sWm[128 * 64];
  __shared__ float sh[4][128];
  int tid = threadIdx.x;
  for (int i = tid; i < 8192; i += 256) sWm[i] = Wm[i];
  __syncthreads();
  int y = tid >> 6, t = tid & 63;
  float g0 = lng[t], g1 = lng[64 + t];
  float b0 = lnb[t], b1 = lnb[64 + t];
  float bmv = bm[t];
  for (int base = blockIdx.x * 4; base < ne; base += gridDim.x * 4) {
    int e = base + y;
    if (e >= ne) continue;  // wave-uniform
    int s = ei[e], d = ei[EE + e];
    float c0 = xout[(size_t)s * 64 + t];
    float c1 = xout[(size_t)d * 64 + t];
    float sm = c0 + c1, sq = c0 * c0 + c1 * c1;
#pragma unroll
    for (int mm = 1; mm < 64; mm <<= 1) {
      sm += __shfl_xor(sm, mm, 64);
      sq += __shfl_xor(sq, mm, 64);
    }
    float mean = sm * (1.f / 128.f);
    float var = sq * (1.f / 128.f) - mean * mean;
    float rs = rsqrtf(var + 1e-5f);
    float h0 = fmaxf((c0 - mean) * rs * g0 + b0, 0.f);
    float h1 = fmaxf((c1 - mean) * rs * g1 + b1, 0.f);
    sh[y][t] = h0;          // wave-local LDS
    sh[y][64 + t] = h1;
    float acc = bmv;
#pragma unroll 16
    for (int k = 0; k < 128; k++) acc += sh[y][k] * sWm[k * 64 + t];
    eout[(size_t)e * 64 + t] = ea[(size_t)e * 64 + t] + acc;
  }
}

extern "C" void kernel_launch(void* const* d_in, const int* in_sizes, int n_in,
                              void* d_out, int out_size, void* d_ws, size_t ws_size,
                              hipStream_t stream) {
  const float* x   = (const float*)d_in[0];
  const int*   ei  = (const int*)d_in[1];
  const float* ea  = (const float*)d_in[2];
  const float* Wl  = (const float*)d_in[3];
  const float* Wr  = (const float*)d_in[4];
  const float* We  = (const float*)d_in[5];
  const float* att = (const float*)d_in[6];
  const float* cb  = (const float*)d_in[7];
  const float* lng = (const float*)d_in[8];
  const float* lnb = (const float*)d_in[9];
  const float* Wm  = (const float*)d_in[10];
  const float* bm  = (const float*)d_in[11];

  float* out  = (float*)d_out;
  float* xout = out;                       // [N,64]
  float* eout = out + (size_t)NN * 64;     // [E,64]

  // scratch layout: xl, xr [N*64 f32 each]; logits [E*4 f32];
  // counts [N], offsets [N+1], cursor [N], edge_of [E] (int32)
  size_t needWords = (size_t)NN * 64 * 2 + (size_t)EE * 4   // floats
                   + (size_t)NN * 3 + 1 + (size_t)EE;       // ints
  size_t needBytes = needWords * 4;
  // fall back into the e_out region of d_out (dead until k_edge_mlp,
  // which reads none of the scratch) if d_ws is too small.
  float* scratch = (ws_size >= needBytes) ? (float*)d_ws : eout;

  float* xl     = scratch;
  float* xr     = xl + (size_t)NN * 64;
  float* logits = xr + (size_t)NN * 64;
  int*   counts  = (int*)(logits + (size_t)EE * 4);
  int*   offsets = counts + NN;
  int*   cursor  = offsets + NN + 1;
  int*   edge_of = cursor + NN;

  hipMemsetAsync(counts, 0, NN * sizeof(int), stream);
  k_node_linear<<<2048, 256, 0, stream>>>(x, Wl, Wr, xl, xr, NN);
  k_edge_logits<<<2048, 256, 0, stream>>>(ea, ei, We, att, xl, xr, logits, counts, EE);
  k_scan<<<1, 1024, 0, stream>>>(counts, offsets, cursor, NN);
  k_scatter<<<1024, 256, 0, stream>>>(ei, cursor, edge_of, EE);
  k_node_agg<<<2048, 256, 0, stream>>>(ei, offsets, edge_of, logits, xl, cb, xout, NN);
  k_edge_mlp<<<2048, 256, 0, stream>>>(ea, ei, xout, lng, lnb, Wm, bm, eout, EE);
}

// Round 2
// 1327.641 us; speedup vs baseline: 1.0554x; 1.0554x over previous
//
#include <hip/hip_runtime.h>
#include <cstdint>
#include <cstddef>

#define NN 50000
#define EE 800000
// D=64, HEADS=4, C=16, 2D=128

// ---------- K1: xl = x@Wl, xr = x@Wr  (lane-per-node, weights via s_load) ----------
__global__ __launch_bounds__(256, 2) void k_node_linear(
    const float* __restrict__ x, const float* __restrict__ Wl,
    const float* __restrict__ Wr, float* __restrict__ xl,
    float* __restrict__ xr, int n) {
  int i = blockIdx.x * 256 + threadIdx.x;
  if (i >= n) return;
  const float4* px = (const float4*)(x + (size_t)i * 64);
  float xv[64];
#pragma unroll
  for (int q = 0; q < 16; q++) {
    float4 v = px[q];
    xv[4 * q] = v.x; xv[4 * q + 1] = v.y; xv[4 * q + 2] = v.z; xv[4 * q + 3] = v.w;
  }
  float accl[64], accr[64];
#pragma unroll
  for (int c = 0; c < 64; c++) { accl[c] = 0.f; accr[c] = 0.f; }
#pragma unroll
  for (int k = 0; k < 64; k++) {
#pragma unroll
    for (int c = 0; c < 64; c++) {
      accl[c] = fmaf(xv[k], Wl[k * 64 + c], accl[c]);   // Wl addr wave-uniform -> s_load
      accr[c] = fmaf(xv[k], Wr[k * 64 + c], accr[c]);
    }
  }
  float4* pl = (float4*)(xl + (size_t)i * 64);
  float4* pr = (float4*)(xr + (size_t)i * 64);
#pragma unroll
  for (int q = 0; q < 16; q++) {
    float4 a, b;
    a.x = accl[4 * q]; a.y = accl[4 * q + 1]; a.z = accl[4 * q + 2]; a.w = accl[4 * q + 3];
    b.x = accr[4 * q]; b.y = accr[4 * q + 1]; b.z = accr[4 * q + 2]; b.w = accr[4 * q + 3];
    pl[q] = a; pr[q] = b;
  }
}

// ---------- K2: logits + counts (lane-per-edge) ----------
__global__ __launch_bounds__(256, 2) void k_edge_logits(
    const float* __restrict__ ea, const int* __restrict__ ei,
    const float* __restrict__ We, const float* __restrict__ att,
    const float* __restrict__ xl, const float* __restrict__ xr,
    float* __restrict__ logits, int* __restrict__ counts, int ne) {
  int e = blockIdx.x * 256 + threadIdx.x;
  if (e >= ne) return;
  int s = ei[e], d = ei[EE + e];
  const float4* pa = (const float4*)(ea + (size_t)e * 64);
  float a[64];
#pragma unroll
  for (int q = 0; q < 16; q++) {
    float4 v = pa[q];
    a[4 * q] = v.x; a[4 * q + 1] = v.y; a[4 * q + 2] = v.z; a[4 * q + 3] = v.w;
  }
  float acc[64];
#pragma unroll
  for (int c = 0; c < 64; c++) acc[c] = 0.f;
#pragma unroll
  for (int k = 0; k < 64; k++) {
#pragma unroll
    for (int c = 0; c < 64; c++)
      acc[c] = fmaf(a[k], We[k * 64 + c], acc[c]);      // wave-uniform -> s_load
  }
  const float4* pxl = (const float4*)(xl + (size_t)s * 64);
  const float4* pxr = (const float4*)(xr + (size_t)d * 64);
  float lgh[4] = {0.f, 0.f, 0.f, 0.f};
#pragma unroll
  for (int q = 0; q < 16; q++) {
    float4 u = pxl[q];
    float4 v = pxr[q];
    float z0 = acc[4 * q] + u.x + v.x;
    float z1 = acc[4 * q + 1] + u.y + v.y;
    float z2 = acc[4 * q + 2] + u.z + v.z;
    float z3 = acc[4 * q + 3] + u.w + v.w;
    z0 = (z0 >= 0.f) ? z0 : 0.2f * z0;
    z1 = (z1 >= 0.f) ? z1 : 0.2f * z1;
    z2 = (z2 >= 0.f) ? z2 : 0.2f * z2;
    z3 = (z3 >= 0.f) ? z3 : 0.2f * z3;
    int h = q >> 2;  // 16 cols per head
    lgh[h] += z0 * att[4 * q] + z1 * att[4 * q + 1] + z2 * att[4 * q + 2] + z3 * att[4 * q + 3];
  }
  float4 lo;
  lo.x = lgh[0]; lo.y = lgh[1]; lo.z = lgh[2]; lo.w = lgh[3];
  ((float4*)logits)[e] = lo;
  atomicAdd(&counts[d], 1);
}

// ---------- K3: exclusive scan (per-thread serial segments) ----------
__global__ __launch_bounds__(1024) void k_scan(const int* __restrict__ counts,
                                               int* __restrict__ offsets,
                                               int* __restrict__ cursor, int n) {
  __shared__ int tmp[1024];
  int tid = threadIdx.x;
  int per = (n + 1023) >> 10;
  int lo = tid * per;
  int hi = lo + per; if (hi > n) hi = n; if (lo > n) lo = n;
  int sum = 0;
  for (int i = lo; i < hi; i++) sum += counts[i];
  tmp[tid] = sum;
  __syncthreads();
  for (int off = 1; off < 1024; off <<= 1) {
    int v = (tid >= off) ? tmp[tid - off] : 0;
    __syncthreads();
    tmp[tid] += v;
    __syncthreads();
  }
  int run = tmp[tid] - sum;  // exclusive prefix of this segment
  for (int i = lo; i < hi; i++) {
    offsets[i] = run; cursor[i] = run; run += counts[i];
  }
  if (tid == 1023) offsets[n] = tmp[1023];
}

// ---------- K4: scatter edge ids into CSR ----------
__global__ __launch_bounds__(256) void k_scatter(const int* __restrict__ ei,
                                                 int* __restrict__ cursor,
                                                 int* __restrict__ edge_of, int ne) {
  int e = blockIdx.x * blockDim.x + threadIdx.x;
  for (; e < ne; e += gridDim.x * blockDim.x) {
    int d = ei[EE + e];
    int pos = atomicAdd(&cursor[d], 1);
    edge_of[pos] = e;
  }
}

// ---------- K5: per-node online segment softmax + aggregate (single pass) ----------
__global__ __launch_bounds__(256) void k_node_agg(
    const int* __restrict__ ei, const int* __restrict__ offsets,
    const int* __restrict__ edge_of, const float* __restrict__ logits,
    const float* __restrict__ xl, const float* __restrict__ bias,
    float* __restrict__ xout, int n) {
  int tid = threadIdx.x;
  int y = tid >> 6, t = tid & 63;
  int h = t >> 4;
  float bv = bias[t];
  for (int base = blockIdx.x * 4; base < n; base += gridDim.x * 4) {
    int i = base + y;
    if (i >= n) continue;  // wave-uniform
    int beg = offsets[i], end = offsets[i + 1];
    float m = -__builtin_inff();
    float den = 0.f, acc = 0.f;
    for (int j = beg; j < end; j++) {
      int e = edge_of[j];      // wave-uniform -> s_load
      int s = ei[e];
      float lg = logits[(size_t)e * 4 + h];
      float xv = xl[(size_t)s * 64 + t];
      float mnew = fmaxf(m, lg);
      float corr = __expf(m - mnew);   // 0 on first iter (m=-inf)
      float p = __expf(lg - mnew);
      den = den * corr + p;
      acc = acc * corr + p * xv;
      m = mnew;
    }
    xout[(size_t)i * 64 + t] = acc / (den + 1e-16f) + bv;
  }
}

// ---------- K6: edge MLP (lane-per-edge, h in regs, weights via s_load) ----------
__global__ __launch_bounds__(256, 2) void k_edge_mlp(
    const float* __restrict__ ea, const int* __restrict__ ei,
    const float* __restrict__ xout, const float* __restrict__ lng,
    const float* __restrict__ lnb, const float* __restrict__ Wm,
    const float* __restrict__ bm, float* __restrict__ eout, int ne) {
  int e = blockIdx.x * 256 + threadIdx.x;
  if (e >= ne) return;
  int s = ei[e], d = ei[EE + e];
  const float4* ps = (const float4*)(xout + (size_t)s * 64);
  const float4* pd = (const float4*)(xout + (size_t)d * 64);
  float hv[128];
  float sm = 0.f, sq = 0.f;
#pragma unroll
  for (int q = 0; q < 16; q++) {
    float4 v = ps[q];
    hv[4 * q] = v.x; hv[4 * q + 1] = v.y; hv[4 * q + 2] = v.z; hv[4 * q + 3] = v.w;
    sm += v.x + v.y + v.z + v.w;
    sq += v.x * v.x + v.y * v.y + v.z * v.z + v.w * v.w;
  }
#pragma unroll
  for (int q = 0; q < 16; q++) {
    float4 v = pd[q];
    hv[64 + 4 * q] = v.x; hv[64 + 4 * q + 1] = v.y; hv[64 + 4 * q + 2] = v.z; hv[64 + 4 * q + 3] = v.w;
    sm += v.x + v.y + v.z + v.w;
    sq += v.x * v.x + v.y * v.y + v.z * v.z + v.w * v.w;
  }
  float mean = sm * (1.f / 128.f);
  float var = sq * (1.f / 128.f) - mean * mean;
  float rs = rsqrtf(var + 1e-5f);
#pragma unroll
  for (int i = 0; i < 128; i++)
    hv[i] = fmaxf((hv[i] - mean) * rs * lng[i] + lnb[i], 0.f);  // lng/lnb -> s_load
  float acc[64];
#pragma unroll
  for (int c = 0; c < 64; c++) acc[c] = bm[c];                  // s_load
#pragma unroll
  for (int k = 0; k < 128; k++) {
#pragma unroll
    for (int c = 0; c < 64; c++)
      acc[c] = fmaf(hv[k], Wm[k * 64 + c], acc[c]);             // wave-uniform -> s_load
  }
  const float4* pe = (const float4*)(ea + (size_t)e * 64);
  float4* po = (float4*)(eout + (size_t)e * 64);
#pragma unroll
  for (int q = 0; q < 16; q++) {
    float4 r = pe[q];
    float4 o;
    o.x = r.x + acc[4 * q];
    o.y = r.y + acc[4 * q + 1];
    o.z = r.z + acc[4 * q + 2];
    o.w = r.w + acc[4 * q + 3];
    po[q] = o;
  }
}

extern "C" void kernel_launch(void* const* d_in, const int* in_sizes, int n_in,
                              void* d_out, int out_size, void* d_ws, size_t ws_size,
                              hipStream_t stream) {
  const float* x   = (const float*)d_in[0];
  const int*   ei  = (const int*)d_in[1];
  const float* ea  = (const float*)d_in[2];
  const float* Wl  = (const float*)d_in[3];
  const float* Wr  = (const float*)d_in[4];
  const float* We  = (const float*)d_in[5];
  const float* att = (const float*)d_in[6];
  const float* cb  = (const float*)d_in[7];
  const float* lng = (const float*)d_in[8];
  const float* lnb = (const float*)d_in[9];
  const float* Wm  = (const float*)d_in[10];
  const float* bm  = (const float*)d_in[11];

  float* out  = (float*)d_out;
  float* xout = out;                       // [N,64]
  float* eout = out + (size_t)NN * 64;     // [E,64]

  size_t needWords = (size_t)NN * 64 * 2 + (size_t)EE * 4   // floats
                   + (size_t)NN * 3 + 1 + (size_t)EE;       // ints
  size_t needBytes = needWords * 4;
  float* scratch = (ws_size >= needBytes) ? (float*)d_ws : eout;

  float* xl     = scratch;
  float* xr     = xl + (size_t)NN * 64;
  float* logits = xr + (size_t)NN * 64;
  int*   counts  = (int*)(logits + (size_t)EE * 4);
  int*   offsets = counts + NN;
  int*   cursor  = offsets + NN + 1;
  int*   edge_of = cursor + NN;

  hipMemsetAsync(counts, 0, NN * sizeof(int), stream);
  k_node_linear<<<(NN + 255) / 256, 256, 0, stream>>>(x, Wl, Wr, xl, xr, NN);
  k_edge_logits<<<(EE + 255) / 256, 256, 0, stream>>>(ea, ei, We, att, xl, xr, logits, counts, EE);
  k_scan<<<1, 1024, 0, stream>>>(counts, offsets, cursor, NN);
  k_scatter<<<1024, 256, 0, stream>>>(ei, cursor, edge_of, EE);
  k_node_agg<<<2048, 256, 0, stream>>>(ei, offsets, edge_of, logits, xl, cb, xout, NN);
  k_edge_mlp<<<(EE + 255) / 256, 256, 0, stream>>>(ea, ei, xout, lng, lnb, Wm, bm, eout, EE);
}

// Round 3
// 1021.272 us; speedup vs baseline: 1.3720x; 1.3000x over previous
//
#include <hip/hip_runtime.h>
#include <cstdint>
#include <cstddef>

#define NN 50000
#define EE 800000
// D=64, HEADS=4, C=16, 2D=128

// ---------- K1: xl = x@Wl, xr = x@Wr  (lane-per-node; acc in regs, weights s_load) ----------
__global__ __launch_bounds__(256, 3) void k_node_linear(
    const float* __restrict__ x, const float* __restrict__ Wl,
    const float* __restrict__ Wr, float* __restrict__ xl,
    float* __restrict__ xr, int n) {
  int i = blockIdx.x * 256 + threadIdx.x;
  if (i >= n) return;
  const float4* px = (const float4*)(x + (size_t)i * 64);
  float accl[64], accr[64];
#pragma unroll
  for (int c = 0; c < 64; c++) { accl[c] = 0.f; accr[c] = 0.f; }
  for (int kq = 0; kq < 16; kq++) {          // runtime loop: acc stays in regs (SROA via inner unroll)
    float4 v = px[kq];
#pragma unroll
    for (int j = 0; j < 4; j++) {
      float xv = (j == 0) ? v.x : (j == 1) ? v.y : (j == 2) ? v.z : v.w;
      const float* wl = Wl + (kq * 4 + j) * 64;   // wave-uniform -> s_load
      const float* wr = Wr + (kq * 4 + j) * 64;
#pragma unroll
      for (int c = 0; c < 64; c++) {
        accl[c] = fmaf(xv, wl[c], accl[c]);
        accr[c] = fmaf(xv, wr[c], accr[c]);
      }
    }
  }
  float4* pl = (float4*)(xl + (size_t)i * 64);
  float4* pr = (float4*)(xr + (size_t)i * 64);
#pragma unroll
  for (int q = 0; q < 16; q++) {
    float4 a, b;
    a.x = accl[4 * q]; a.y = accl[4 * q + 1]; a.z = accl[4 * q + 2]; a.w = accl[4 * q + 3];
    b.x = accr[4 * q]; b.y = accr[4 * q + 1]; b.z = accr[4 * q + 2]; b.w = accr[4 * q + 3];
    pl[q] = a; pr[q] = b;
  }
}

// ---------- K2: logits + counts (lane-per-edge; acc[64] regs, We rows via s_load) ----------
__global__ __launch_bounds__(256, 3) void k_edge_logits(
    const float* __restrict__ ea, const int* __restrict__ ei,
    const float* __restrict__ We, const float* __restrict__ att,
    const float* __restrict__ xl, const float* __restrict__ xr,
    float* __restrict__ logits, int* __restrict__ counts, int ne) {
  int e = blockIdx.x * 256 + threadIdx.x;
  if (e >= ne) return;
  int s = ei[e], d = ei[EE + e];
  const float4* pa = (const float4*)(ea + (size_t)e * 64);
  float acc[64];
#pragma unroll
  for (int c = 0; c < 64; c++) acc[c] = 0.f;
  for (int kq = 0; kq < 16; kq++) {          // runtime loop
    float4 v = pa[kq];
#pragma unroll
    for (int j = 0; j < 4; j++) {
      float av = (j == 0) ? v.x : (j == 1) ? v.y : (j == 2) ? v.z : v.w;
      const float* wr = We + (kq * 4 + j) * 64;   // wave-uniform -> s_load
#pragma unroll
      for (int c = 0; c < 64; c++) acc[c] = fmaf(av, wr[c], acc[c]);
    }
  }
  const float4* pxl = (const float4*)(xl + (size_t)s * 64);
  const float4* pxr = (const float4*)(xr + (size_t)d * 64);
  float lgh[4] = {0.f, 0.f, 0.f, 0.f};
#pragma unroll
  for (int q = 0; q < 16; q++) {
    float4 u = pxl[q];
    float4 v = pxr[q];
    float z0 = acc[4 * q] + u.x + v.x;
    float z1 = acc[4 * q + 1] + u.y + v.y;
    float z2 = acc[4 * q + 2] + u.z + v.z;
    float z3 = acc[4 * q + 3] + u.w + v.w;
    z0 = (z0 >= 0.f) ? z0 : 0.2f * z0;
    z1 = (z1 >= 0.f) ? z1 : 0.2f * z1;
    z2 = (z2 >= 0.f) ? z2 : 0.2f * z2;
    z3 = (z3 >= 0.f) ? z3 : 0.2f * z3;
    lgh[q >> 2] += z0 * att[4 * q] + z1 * att[4 * q + 1] + z2 * att[4 * q + 2] + z3 * att[4 * q + 3];
  }
  float4 lo;
  lo.x = lgh[0]; lo.y = lgh[1]; lo.z = lgh[2]; lo.w = lgh[3];
  ((float4*)logits)[e] = lo;
  atomicAdd(&counts[d], 1);
}

// ---------- K3: exclusive scan (per-thread serial segments) ----------
__global__ __launch_bounds__(1024) void k_scan(const int* __restrict__ counts,
                                               int* __restrict__ offsets,
                                               int* __restrict__ cursor, int n) {
  __shared__ int tmp[1024];
  int tid = threadIdx.x;
  int per = (n + 1023) >> 10;
  int lo = tid * per;
  int hi = lo + per; if (hi > n) hi = n; if (lo > n) lo = n;
  int sum = 0;
  for (int i = lo; i < hi; i++) sum += counts[i];
  tmp[tid] = sum;
  __syncthreads();
  for (int off = 1; off < 1024; off <<= 1) {
    int v = (tid >= off) ? tmp[tid - off] : 0;
    __syncthreads();
    tmp[tid] += v;
    __syncthreads();
  }
  int run = tmp[tid] - sum;  // exclusive prefix of this segment
  for (int i = lo; i < hi; i++) {
    offsets[i] = run; cursor[i] = run; run += counts[i];
  }
  if (tid == 1023) offsets[n] = tmp[1023];
}

// ---------- K4: scatter edge ids into CSR ----------
__global__ __launch_bounds__(256) void k_scatter(const int* __restrict__ ei,
                                                 int* __restrict__ cursor,
                                                 int* __restrict__ edge_of, int ne) {
  int e = blockIdx.x * blockDim.x + threadIdx.x;
  for (; e < ne; e += gridDim.x * blockDim.x) {
    int d = ei[EE + e];
    int pos = atomicAdd(&cursor[d], 1);
    edge_of[pos] = e;
  }
}

// ---------- K5: per-node online segment softmax + aggregate (single pass) ----------
__global__ __launch_bounds__(256) void k_node_agg(
    const int* __restrict__ ei, const int* __restrict__ offsets,
    const int* __restrict__ edge_of, const float* __restrict__ logits,
    const float* __restrict__ xl, const float* __restrict__ bias,
    float* __restrict__ xout, int n) {
  int tid = threadIdx.x;
  int y = tid >> 6, t = tid & 63;
  int h = t >> 4;
  float bv = bias[t];
  for (int base = blockIdx.x * 4; base < n; base += gridDim.x * 4) {
    int i = base + y;
    if (i >= n) continue;  // wave-uniform
    int beg = offsets[i], end = offsets[i + 1];
    float m = -__builtin_inff();
    float den = 0.f, acc = 0.f;
    for (int j = beg; j < end; j++) {
      int e = edge_of[j];      // wave-uniform -> s_load
      int s = ei[e];
      float lg = logits[(size_t)e * 4 + h];
      float xv = xl[(size_t)s * 64 + t];
      float mnew = fmaxf(m, lg);
      float corr = __expf(m - mnew);   // 0 on first iter (m=-inf)
      float p = __expf(lg - mnew);
      den = den * corr + p;
      acc = acc * corr + p * xv;
      m = mnew;
    }
    xout[(size_t)i * 64 + t] = acc / (den + 1e-16f) + bv;
  }
}

// ---------- K6: edge MLP (lane-per-edge; acc[64] regs; h normalized on the fly) ----------
__global__ __launch_bounds__(256, 3) void k_edge_mlp(
    const float* __restrict__ ea, const int* __restrict__ ei,
    const float* __restrict__ xout, const float* __restrict__ lng,
    const float* __restrict__ lnb, const float* __restrict__ Wm,
    const float* __restrict__ bm, float* __restrict__ eout, int ne) {
  int e = blockIdx.x * 256 + threadIdx.x;
  if (e >= ne) return;
  int s = ei[e], d = ei[EE + e];
  const float4* ps = (const float4*)(xout + (size_t)s * 64);
  const float4* pd = (const float4*)(xout + (size_t)d * 64);
  // phase A: LN stats (streamed; rows stay hot in L1/L2 for phase B)
  float sm = 0.f, sq = 0.f;
  for (int q = 0; q < 16; q++) {
    float4 v = ps[q];
    sm += v.x + v.y + v.z + v.w;
    sq += v.x * v.x + v.y * v.y + v.z * v.z + v.w * v.w;
  }
  for (int q = 0; q < 16; q++) {
    float4 v = pd[q];
    sm += v.x + v.y + v.z + v.w;
    sq += v.x * v.x + v.y * v.y + v.z * v.z + v.w * v.w;
  }
  float mean = sm * (1.f / 128.f);
  float var = sq * (1.f / 128.f) - mean * mean;
  float rs = rsqrtf(var + 1e-5f);
  // phase B: acc[c] = bm[c] + sum_k h[k] * Wm[k][c], h computed on the fly
  float acc[64];
#pragma unroll
  for (int c = 0; c < 64; c++) acc[c] = bm[c];   // s_load
  for (int kq = 0; kq < 32; kq++) {              // runtime loop over 128 k in float4 chunks
    float4 v = (kq < 16) ? ps[kq] : pd[kq - 16];
#pragma unroll
    for (int j = 0; j < 4; j++) {
      int k = kq * 4 + j;
      float hv = (j == 0) ? v.x : (j == 1) ? v.y : (j == 2) ? v.z : v.w;
      hv = fmaxf((hv - mean) * rs * lng[k] + lnb[k], 0.f);   // lng/lnb s_load
      const float* wr = Wm + k * 64;                          // wave-uniform -> s_load
#pragma unroll
      for (int c = 0; c < 64; c++) acc[c] = fmaf(hv, wr[c], acc[c]);
    }
  }
  const float4* pe = (const float4*)(ea + (size_t)e * 64);
  float4* po = (float4*)(eout + (size_t)e * 64);
#pragma unroll
  for (int q = 0; q < 16; q++) {
    float4 r = pe[q];
    float4 o;
    o.x = r.x + acc[4 * q];
    o.y = r.y + acc[4 * q + 1];
    o.z = r.z + acc[4 * q + 2];
    o.w = r.w + acc[4 * q + 3];
    po[q] = o;
  }
}

extern "C" void kernel_launch(void* const* d_in, const int* in_sizes, int n_in,
                              void* d_out, int out_size, void* d_ws, size_t ws_size,
                              hipStream_t stream) {
  const float* x   = (const float*)d_in[0];
  const int*   ei  = (const int*)d_in[1];
  const float* ea  = (const float*)d_in[2];
  const float* Wl  = (const float*)d_in[3];
  const float* Wr  = (const float*)d_in[4];
  const float* We  = (const float*)d_in[5];
  const float* att = (const float*)d_in[6];
  const float* cb  = (const float*)d_in[7];
  const float* lng = (const float*)d_in[8];
  const float* lnb = (const float*)d_in[9];
  const float* Wm  = (const float*)d_in[10];
  const float* bm  = (const float*)d_in[11];

  float* out  = (float*)d_out;
  float* xout = out;                       // [N,64]
  float* eout = out + (size_t)NN * 64;     // [E,64]

  size_t needWords = (size_t)NN * 64 * 2 + (size_t)EE * 4   // floats
                   + (size_t)NN * 3 + 1 + (size_t)EE;       // ints
  size_t needBytes = needWords * 4;
  float* scratch = (ws_size >= needBytes) ? (float*)d_ws : eout;

  float* xl     = scratch;
  float* xr     = xl + (size_t)NN * 64;
  float* logits = xr + (size_t)NN * 64;
  int*   counts  = (int*)(logits + (size_t)EE * 4);
  int*   offsets = counts + NN;
  int*   cursor  = offsets + NN + 1;
  int*   edge_of = cursor + NN;

  hipMemsetAsync(counts, 0, NN * sizeof(int), stream);
  k_node_linear<<<(NN + 255) / 256, 256, 0, stream>>>(x, Wl, Wr, xl, xr, NN);
  k_edge_logits<<<(EE + 255) / 256, 256, 0, stream>>>(ea, ei, We, att, xl, xr, logits, counts, EE);
  k_scan<<<1, 1024, 0, stream>>>(counts, offsets, cursor, NN);
  k_scatter<<<1024, 256, 0, stream>>>(ei, cursor, edge_of, EE);
  k_node_agg<<<2048, 256, 0, stream>>>(ei, offsets, edge_of, logits, xl, cb, xout, NN);
  k_edge_mlp<<<(EE + 255) / 256, 256, 0, stream>>>(ea, ei, xout, lng, lnb, Wm, bm, eout, EE);
}

// Round 4
// 631.759 us; speedup vs baseline: 2.2180x; 1.6166x over previous
//
#include <hip/hip_runtime.h>
#include <cstdint>
#include <cstddef>

#define NN 50000
#define EE 800000
// D=64, HEADS=4, C=16, 2D=128. E = 32*25000 exactly.

typedef short bf16x8 __attribute__((ext_vector_type(8)));
typedef float f32x4 __attribute__((ext_vector_type(4)));

__device__ __forceinline__ ushort f2b(float f) {   // f32 -> bf16 RNE
  uint u = __builtin_bit_cast(uint, f);
  u += 0x7FFFu + ((u >> 16) & 1u);
  return (ushort)(u >> 16);
}
__device__ __forceinline__ float b2f(ushort h) {
  return __builtin_bit_cast(float, ((uint)h) << 16);
}
__device__ __forceinline__ uint pk2(float a, float b) {
  return (uint)f2b(a) | (((uint)f2b(b)) << 16);
}

// ---------- K1: xl = x@Wl, xr = x@Wr ----------
__global__ __launch_bounds__(256) void k_node_linear(
    const float* __restrict__ x, const float* __restrict__ Wl,
    const float* __restrict__ Wr, float* __restrict__ xl,
    float* __restrict__ xr, int n) {
  int i = blockIdx.x * 256 + threadIdx.x;
  if (i >= n) return;
  const float4* px = (const float4*)(x + (size_t)i * 64);
  float accl[64], accr[64];
#pragma unroll
  for (int c = 0; c < 64; c++) { accl[c] = 0.f; accr[c] = 0.f; }
  for (int kq = 0; kq < 16; kq++) {
    float4 v = px[kq];
#pragma unroll
    for (int j = 0; j < 4; j++) {
      float xv = (j == 0) ? v.x : (j == 1) ? v.y : (j == 2) ? v.z : v.w;
      const float* wl = Wl + (kq * 4 + j) * 64;
      const float* wr = Wr + (kq * 4 + j) * 64;
#pragma unroll
      for (int c = 0; c < 64; c++) {
        accl[c] = fmaf(xv, wl[c], accl[c]);
        accr[c] = fmaf(xv, wr[c], accr[c]);
      }
    }
  }
  float4* pl = (float4*)(xl + (size_t)i * 64);
  float4* pr = (float4*)(xr + (size_t)i * 64);
#pragma unroll
  for (int q = 0; q < 16; q++) {
    float4 a, b;
    a.x = accl[4 * q]; a.y = accl[4 * q + 1]; a.z = accl[4 * q + 2]; a.w = accl[4 * q + 3];
    b.x = accr[4 * q]; b.y = accr[4 * q + 1]; b.z = accr[4 * q + 2]; b.w = accr[4 * q + 3];
    pl[q] = a; pr[q] = b;
  }
}

// ---------- K2: logits via MFMA (swapped operands: D[col][edge]) ----------
// ef = ea @ We (bf16 MFMA), z = lrelu(ef + xl[s] + xr[d]), logits[e][h] = sum_c z*att
__global__ __launch_bounds__(256) void k_edge_logits(
    const float* __restrict__ ea, const int* __restrict__ ei,
    const float* __restrict__ We, const float* __restrict__ att,
    const float* __restrict__ xl, const float* __restrict__ xr,
    float* __restrict__ logits, int* __restrict__ counts) {
  __shared__ uint4 sA[4][32 * 8];    // [wave][edge][chunk of 8 bf16], chunk XOR-swizzled
  __shared__ float sX[4][32 * 69];   // xl[s]+xr[d] rows, stride 69 (bank-spread)
  int tid = threadIdx.x;
  int w = tid >> 6, l = tid & 63;
  int lo16 = l & 15, hi4 = l >> 4;
  int base = (blockIdx.x * 4 + w) * 32;

  // We fragments: frag(n,s) elem j = We[s*32 + hi4*8 + j][lo16 + 16n]  (A-operand, M=col)
  bf16x8 bw[4][2];
  for (int n = 0; n < 4; n++)
    for (int s = 0; s < 2; s++) {
      bf16x8 t;
#pragma unroll
      for (int j = 0; j < 8; j++)
        t[j] = (short)f2b(We[(s * 32 + hi4 * 8 + j) * 64 + lo16 + 16 * n]);
      bw[n][s] = t;
    }
  float att4[4][4];
  for (int n = 0; n < 4; n++)
    for (int r = 0; r < 4; r++) att4[n][r] = att[hi4 * 4 + r + 16 * n];

  // phase 1: lane-pair per edge; ea row -> bf16 LDS; xl[s]+xr[d] -> f32 LDS
  int g = l >> 1, h = l & 1;
  int e = base + g;
  int sj = ei[e], dj = ei[EE + e];
  {
    const float4* pa = (const float4*)(ea + (size_t)e * 64 + 32 * h);
#pragma unroll
    for (int c = 0; c < 4; c++) {
      float4 v0 = pa[2 * c], v1 = pa[2 * c + 1];
      uint4 u;
      u.x = pk2(v0.x, v0.y); u.y = pk2(v0.z, v0.w);
      u.z = pk2(v1.x, v1.y); u.w = pk2(v1.z, v1.w);
      sA[w][g * 8 + ((4 * h + c) ^ (g & 7))] = u;
    }
    const float4* pl = (const float4*)(xl + (size_t)sj * 64 + 32 * h);
    const float4* pr = (const float4*)(xr + (size_t)dj * 64 + 32 * h);
#pragma unroll
    for (int c = 0; c < 8; c++) {
      float4 a = pl[c], b = pr[c];
      float* dst = &sX[w][g * 69 + 32 * h + 4 * c];
      dst[0] = a.x + b.x; dst[1] = a.y + b.y; dst[2] = a.z + b.z; dst[3] = a.w + b.w;
    }
    if (h == 0) atomicAdd(&counts[dj], 1);
  }
  // phase 2 (wave-local LDS dependence; compiler inserts lgkm waits)
  for (int te = 0; te < 2; te++) {
    f32x4 z4 = {0.f, 0.f, 0.f, 0.f};
    f32x4 acc[4] = {z4, z4, z4, z4};
    int edge = lo16 + 16 * te;
#pragma unroll
    for (int s2 = 0; s2 < 2; s2++) {
      uint4 av = sA[w][edge * 8 + ((s2 * 4 + hi4) ^ (edge & 7))];
      bf16x8 a = __builtin_bit_cast(bf16x8, av);
#pragma unroll
      for (int n = 0; n < 4; n++)
        acc[n] = __builtin_amdgcn_mfma_f32_16x16x32_bf16(bw[n][s2], a, acc[n], 0, 0, 0);
    }
    // D[m=col-in-tile][n=edge]: lane edge = lo16+16te, col = hi4*4 + r + 16n
    float lg[4];
#pragma unroll
    for (int n = 0; n < 4; n++) {
      float s = 0.f;
#pragma unroll
      for (int r = 0; r < 4; r++) {
        float z = acc[n][r] + sX[w][edge * 69 + hi4 * 4 + r + 16 * n];
        z = (z >= 0.f) ? z : 0.2f * z;
        s += z * att4[n][r];
      }
      s += __shfl_xor(s, 16, 64);
      s += __shfl_xor(s, 32, 64);
      lg[n] = s;
    }
    if (l < 16) {
      float4 o; o.x = lg[0]; o.y = lg[1]; o.z = lg[2]; o.w = lg[3];
      ((float4*)logits)[base + 16 * te + lo16] = o;
    }
  }
}

// ---------- K3: exclusive scan ----------
__global__ __launch_bounds__(1024) void k_scan(const int* __restrict__ counts,
                                               int* __restrict__ offsets,
                                               int* __restrict__ cursor, int n) {
  __shared__ int tmp[1024];
  int tid = threadIdx.x;
  int per = (n + 1023) >> 10;
  int lo = tid * per;
  int hi = lo + per; if (hi > n) hi = n; if (lo > n) lo = n;
  int sum = 0;
  for (int i = lo; i < hi; i++) sum += counts[i];
  tmp[tid] = sum;
  __syncthreads();
  for (int off = 1; off < 1024; off <<= 1) {
    int v = (tid >= off) ? tmp[tid - off] : 0;
    __syncthreads();
    tmp[tid] += v;
    __syncthreads();
  }
  int run = tmp[tid] - sum;
  for (int i = lo; i < hi; i++) {
    offsets[i] = run; cursor[i] = run; run += counts[i];
  }
  if (tid == 1023) offsets[n] = tmp[1023];
}

// ---------- K4: scatter edge ids into CSR ----------
__global__ __launch_bounds__(256) void k_scatter(const int* __restrict__ ei,
                                                 int* __restrict__ cursor,
                                                 int* __restrict__ edge_of, int ne) {
  int e = blockIdx.x * blockDim.x + threadIdx.x;
  for (; e < ne; e += gridDim.x * blockDim.x) {
    int d = ei[EE + e];
    int pos = atomicAdd(&cursor[d], 1);
    edge_of[pos] = e;
  }
}

// ---------- K5: per-node online segment softmax + aggregate (+ bf16 x_out copy) ----------
__global__ __launch_bounds__(256) void k_node_agg(
    const int* __restrict__ ei, const int* __restrict__ offsets,
    const int* __restrict__ edge_of, const float* __restrict__ logits,
    const float* __restrict__ xl, const float* __restrict__ bias,
    float* __restrict__ xout, ushort* __restrict__ xb, int n) {
  int tid = threadIdx.x;
  int y = tid >> 6, t = tid & 63;
  int h = t >> 4;
  float bv = bias[t];
  for (int base = blockIdx.x * 4; base < n; base += gridDim.x * 4) {
    int i = base + y;
    if (i >= n) continue;  // wave-uniform
    int beg = offsets[i], end = offsets[i + 1];
    float m = -__builtin_inff();
    float den = 0.f, acc = 0.f;
    for (int j = beg; j < end; j++) {
      int e = edge_of[j];
      int s = ei[e];
      float lg = logits[(size_t)e * 4 + h];
      float xv = xl[(size_t)s * 64 + t];
      float mnew = fmaxf(m, lg);
      float corr = __expf(m - mnew);
      float p = __expf(lg - mnew);
      den = den * corr + p;
      acc = acc * corr + p * xv;
      m = mnew;
    }
    float o = acc / (den + 1e-16f) + bv;
    xout[(size_t)i * 64 + t] = o;
    if (xb) xb[(size_t)i * 64 + t] = f2b(o);
  }
}

// ---------- K6: edge MLP via MFMA ----------
// h = relu(LN(concat(xout[s], xout[d]))); eout = ea + h @ Wm + bm
template <bool BF>
__global__ __launch_bounds__(256) void k_edge_mlp(
    const float* __restrict__ ea, const int* __restrict__ ei,
    const float* __restrict__ xoutf, const ushort* __restrict__ xb,
    const float* __restrict__ lng, const float* __restrict__ lnb,
    const float* __restrict__ Wm, const float* __restrict__ bm,
    float* __restrict__ eout) {
  __shared__ uint4 sA[4][32 * 16];   // [wave][edge][chunk of 8 bf16], swizzled
  int tid = threadIdx.x;
  int w = tid >> 6, l = tid & 63;
  int lo16 = l & 15, hi4 = l >> 4;
  int base = (blockIdx.x * 4 + w) * 32;

  // Wm fragments (B-operand): frag(n,s) elem j = Wm[s*32 + hi4*8 + j][lo16 + 16n]
  bf16x8 bwm[4][4];
  for (int n = 0; n < 4; n++)
    for (int s = 0; s < 4; s++) {
      bf16x8 t;
#pragma unroll
      for (int j = 0; j < 8; j++)
        t[j] = (short)f2b(Wm[(s * 32 + hi4 * 8 + j) * 64 + lo16 + 16 * n]);
      bwm[n][s] = t;
    }
  float bmv[4];
  for (int n = 0; n < 4; n++) bmv[n] = bm[lo16 + 16 * n];

  // phase 1: lane-pair per edge; gather rows, LN stats, normalize -> bf16 LDS
  int g = l >> 1, h = l & 1;
  int e = base + g;
  int sj = ei[e], dj = ei[EE + e];
  float vs[32], vd[32];
  if (BF) {
    const uint4* ps = (const uint4*)(xb + (size_t)sj * 64 + 32 * h);
    const uint4* pd = (const uint4*)(xb + (size_t)dj * 64 + 32 * h);
#pragma unroll
    for (int c = 0; c < 4; c++) {
      uint4 u = ps[c];
      uint uu[4] = {u.x, u.y, u.z, u.w};
#pragma unroll
      for (int q = 0; q < 4; q++) {
        vs[8 * c + 2 * q]     = b2f((ushort)(uu[q] & 0xFFFF));
        vs[8 * c + 2 * q + 1] = b2f((ushort)(uu[q] >> 16));
      }
      uint4 v = pd[c];
      uint vv[4] = {v.x, v.y, v.z, v.w};
#pragma unroll
      for (int q = 0; q < 4; q++) {
        vd[8 * c + 2 * q]     = b2f((ushort)(vv[q] & 0xFFFF));
        vd[8 * c + 2 * q + 1] = b2f((ushort)(vv[q] >> 16));
      }
    }
  } else {
    const float4* ps = (const float4*)(xoutf + (size_t)sj * 64 + 32 * h);
    const float4* pd = (const float4*)(xoutf + (size_t)dj * 64 + 32 * h);
#pragma unroll
    for (int c = 0; c < 8; c++) {
      float4 a = ps[c];
      vs[4 * c] = a.x; vs[4 * c + 1] = a.y; vs[4 * c + 2] = a.z; vs[4 * c + 3] = a.w;
      float4 b = pd[c];
      vd[4 * c] = b.x; vd[4 * c + 1] = b.y; vd[4 * c + 2] = b.z; vd[4 * c + 3] = b.w;
    }
  }
  float sm = 0.f, sq = 0.f;
#pragma unroll
  for (int i = 0; i < 32; i++) {
    sm += vs[i] + vd[i];
    sq += vs[i] * vs[i] + vd[i] * vd[i];
  }
  sm += __shfl_xor(sm, 1, 64);
  sq += __shfl_xor(sq, 1, 64);
  float mean = sm * (1.f / 128.f);
  float var = sq * (1.f / 128.f) - mean * mean;
  float rs = rsqrtf(var + 1e-5f);
#pragma unroll
  for (int c = 0; c < 4; c++) {   // s-row: k = 32h + 8c + j, chunk kc = 4h + c
    float hv[8];
#pragma unroll
    for (int j = 0; j < 8; j++) {
      int k = 32 * h + 8 * c + j;
      hv[j] = fmaxf((vs[8 * c + j] - mean) * rs * lng[k] + lnb[k], 0.f);
    }
    uint4 u;
    u.x = pk2(hv[0], hv[1]); u.y = pk2(hv[2], hv[3]);
    u.z = pk2(hv[4], hv[5]); u.w = pk2(hv[6], hv[7]);
    sA[w][g * 16 + ((4 * h + c) ^ (g & 7))] = u;
  }
#pragma unroll
  for (int c = 0; c < 4; c++) {   // d-row: k = 64 + 32h + 8c + j, chunk kc = 8 + 4h + c
    float hv[8];
#pragma unroll
    for (int j = 0; j < 8; j++) {
      int k = 64 + 32 * h + 8 * c + j;
      hv[j] = fmaxf((vd[8 * c + j] - mean) * rs * lng[k] + lnb[k], 0.f);
    }
    uint4 u;
    u.x = pk2(hv[0], hv[1]); u.y = pk2(hv[2], hv[3]);
    u.z = pk2(hv[4], hv[5]); u.w = pk2(hv[6], hv[7]);
    sA[w][g * 16 + ((8 + 4 * h + c) ^ (g & 7))] = u;
  }
  // phase 2: D[m=edge][n=col]
  for (int t = 0; t < 2; t++) {
    f32x4 z4 = {0.f, 0.f, 0.f, 0.f};
    f32x4 acc[4] = {z4, z4, z4, z4};
    int arow = lo16 + 16 * t;
#pragma unroll
    for (int s2 = 0; s2 < 4; s2++) {
      uint4 av = sA[w][arow * 16 + ((s2 * 4 + hi4) ^ (arow & 7))];
      bf16x8 a = __builtin_bit_cast(bf16x8, av);
#pragma unroll
      for (int n = 0; n < 4; n++)
        acc[n] = __builtin_amdgcn_mfma_f32_16x16x32_bf16(a, bwm[n][s2], acc[n], 0, 0, 0);
    }
#pragma unroll
    for (int n = 0; n < 4; n++) {
#pragma unroll
      for (int r = 0; r < 4; r++) {
        int e2 = base + 16 * t + hi4 * 4 + r;
        size_t off = (size_t)e2 * 64 + lo16 + 16 * n;
        eout[off] = ea[off] + acc[n][r] + bmv[n];
      }
    }
  }
}

extern "C" void kernel_launch(void* const* d_in, const int* in_sizes, int n_in,
                              void* d_out, int out_size, void* d_ws, size_t ws_size,
                              hipStream_t stream) {
  const float* x   = (const float*)d_in[0];
  const int*   ei  = (const int*)d_in[1];
  const float* ea  = (const float*)d_in[2];
  const float* Wl  = (const float*)d_in[3];
  const float* Wr  = (const float*)d_in[4];
  const float* We  = (const float*)d_in[5];
  const float* att = (const float*)d_in[6];
  const float* cb  = (const float*)d_in[7];
  const float* lng = (const float*)d_in[8];
  const float* lnb = (const float*)d_in[9];
  const float* Wm  = (const float*)d_in[10];
  const float* bm  = (const float*)d_in[11];

  float* out  = (float*)d_out;
  float* xout = out;                       // [N,64]
  float* eout = out + (size_t)NN * 64;     // [E,64]

  // scratch: xl, xr [N*64 f], logits [E*4 f], xb [N*64 bf16], ints
  size_t fWords   = (size_t)NN * 64 * 2 + (size_t)EE * 4;
  size_t xbWords  = (size_t)NN * 64 / 2;                 // ushort -> half words
  size_t intWords = (size_t)NN * 3 + 1 + (size_t)EE;
  size_t needBytes = (fWords + xbWords + intWords) * 4;
  bool useWs = (ws_size >= needBytes);
  float* scratch = useWs ? (float*)d_ws : eout;

  float*  xl      = scratch;
  float*  xr      = xl + (size_t)NN * 64;
  float*  logits  = xr + (size_t)NN * 64;
  ushort* xb      = useWs ? (ushort*)(logits + (size_t)EE * 4) : nullptr;
  int*    counts  = useWs ? (int*)(xb + (size_t)NN * 64)
                          : (int*)(logits + (size_t)EE * 4);
  int*    offsets = counts + NN;
  int*    cursor  = offsets + NN + 1;
  int*    edge_of = cursor + NN;

  hipMemsetAsync(counts, 0, NN * sizeof(int), stream);
  k_node_linear<<<(NN + 255) / 256, 256, 0, stream>>>(x, Wl, Wr, xl, xr, NN);
  k_edge_logits<<<EE / 128, 256, 0, stream>>>(ea, ei, We, att, xl, xr, logits, counts);
  k_scan<<<1, 1024, 0, stream>>>(counts, offsets, cursor, NN);
  k_scatter<<<1024, 256, 0, stream>>>(ei, cursor, edge_of, EE);
  k_node_agg<<<2048, 256, 0, stream>>>(ei, offsets, edge_of, logits, xl, cb, xout, xb, NN);
  if (useWs)
    k_edge_mlp<true><<<EE / 128, 256, 0, stream>>>(ea, ei, xout, xb, lng, lnb, Wm, bm, eout);
  else
    k_edge_mlp<false><<<EE / 128, 256, 0, stream>>>(ea, ei, xout, nullptr, lng, lnb, Wm, bm, eout);
}

// Round 5
// 534.150 us; speedup vs baseline: 2.6233x; 1.1827x over previous
//
#include <hip/hip_runtime.h>
#include <cstdint>
#include <cstddef>

#define NN 50000
#define EE 800000
#define NT 10   // 16-edge tiles per wave in edge kernels; 1250 blocks * 4 waves * NT * 16 == EE

typedef short bf16x8 __attribute__((ext_vector_type(8)));
typedef float f32x4 __attribute__((ext_vector_type(4)));

static __device__ __forceinline__ ushort f2b(float f) {
  uint u = __builtin_bit_cast(uint, f);
  u += 0x7FFFu + ((u >> 16) & 1u);
  return (ushort)(u >> 16);
}
static __device__ __forceinline__ float b2f(ushort h) {
  return __builtin_bit_cast(float, ((uint)h) << 16);
}
static __device__ __forceinline__ uint pk2(float a, float b) {
  return (uint)f2b(a) | (((uint)f2b(b)) << 16);
}
static __device__ __forceinline__ void up8(uint4 u, float* o) {
  o[0] = b2f((ushort)(u.x & 0xFFFF)); o[1] = b2f((ushort)(u.x >> 16));
  o[2] = b2f((ushort)(u.y & 0xFFFF)); o[3] = b2f((ushort)(u.y >> 16));
  o[4] = b2f((ushort)(u.z & 0xFFFF)); o[5] = b2f((ushort)(u.z >> 16));
  o[6] = b2f((ushort)(u.w & 0xFFFF)); o[7] = b2f((ushort)(u.w >> 16));
}

// ---------- K0: pack Wm/We into MFMA frag-ordered uint4 tables ----------
// wmP[(s2*4+n)*64 + lane] : elem j = bf16(Wm[(s2*32 + (lane>>4)*8 + j)*64 + (lane&15) + 16n])
// weP[(s*4+n)*64 + lane]  : elem j = bf16(We[(s*32  + (lane>>4)*8 + j)*64 + (lane&15) + 16n])
__global__ __launch_bounds__(256) void k_prep(const float* __restrict__ Wm,
                                              const float* __restrict__ We,
                                              uint4* __restrict__ wmP,
                                              uint4* __restrict__ weP) {
  int idx = blockIdx.x * 256 + threadIdx.x;  // 6 blocks * 256 = 1536
  if (idx < 1024) {
    int s2 = idx >> 8, n = (idx >> 6) & 3, lane = idx & 63;
    int lo = lane & 15, hi = lane >> 4;
    ushort h[8];
#pragma unroll
    for (int j = 0; j < 8; j++) h[j] = f2b(Wm[(s2 * 32 + hi * 8 + j) * 64 + lo + 16 * n]);
    uint4 u;
    u.x = (uint)h[0] | ((uint)h[1] << 16); u.y = (uint)h[2] | ((uint)h[3] << 16);
    u.z = (uint)h[4] | ((uint)h[5] << 16); u.w = (uint)h[6] | ((uint)h[7] << 16);
    wmP[idx] = u;
  } else if (idx < 1536) {
    int k = idx - 1024;
    int s = k >> 8, n = (k >> 6) & 3, lane = k & 63;
    int lo = lane & 15, hi = lane >> 4;
    ushort h[8];
#pragma unroll
    for (int j = 0; j < 8; j++) h[j] = f2b(We[(s * 32 + hi * 8 + j) * 64 + lo + 16 * n]);
    uint4 u;
    u.x = (uint)h[0] | ((uint)h[1] << 16); u.y = (uint)h[2] | ((uint)h[3] << 16);
    u.z = (uint)h[4] | ((uint)h[5] << 16); u.w = (uint)h[6] | ((uint)h[7] << 16);
    weP[k] = u;
  }
}

// ---------- K1: xl = x@Wl, xr = x@Wr (f32, known-working) ----------
__global__ __launch_bounds__(256, 3) void k_node_linear(
    const float* __restrict__ x, const float* __restrict__ Wl,
    const float* __restrict__ Wr, float* __restrict__ xl,
    float* __restrict__ xr, int n) {
  int i = blockIdx.x * 256 + threadIdx.x;
  if (i >= n) return;
  const float4* px = (const float4*)(x + (size_t)i * 64);
  float accl[64], accr[64];
#pragma unroll
  for (int c = 0; c < 64; c++) { accl[c] = 0.f; accr[c] = 0.f; }
  for (int kq = 0; kq < 16; kq++) {
    float4 v = px[kq];
#pragma unroll
    for (int j = 0; j < 4; j++) {
      float xv = (j == 0) ? v.x : (j == 1) ? v.y : (j == 2) ? v.z : v.w;
      const float* wl = Wl + (kq * 4 + j) * 64;
      const float* wr = Wr + (kq * 4 + j) * 64;
#pragma unroll
      for (int c = 0; c < 64; c++) {
        accl[c] = fmaf(xv, wl[c], accl[c]);
        accr[c] = fmaf(xv, wr[c], accr[c]);
      }
    }
  }
  float4* pl = (float4*)(xl + (size_t)i * 64);
  float4* pr = (float4*)(xr + (size_t)i * 64);
#pragma unroll
  for (int q = 0; q < 16; q++) {
    float4 a, b;
    a.x = accl[4 * q]; a.y = accl[4 * q + 1]; a.z = accl[4 * q + 2]; a.w = accl[4 * q + 3];
    b.x = accr[4 * q]; b.y = accr[4 * q + 1]; b.z = accr[4 * q + 2]; b.w = accr[4 * q + 3];
    pl[q] = a; pr[q] = b;
  }
}

// ---------- K2: logits via MFMA, LDS-free (swapped operands: D[col][edge]) ----------
template <bool PACKED>
__global__ __launch_bounds__(256) void k_edge_logits(
    const float* __restrict__ ea, const int* __restrict__ ei,
    const float* __restrict__ We, const float* __restrict__ att,
    const float* __restrict__ xl, const float* __restrict__ xr,
    const uint4* __restrict__ weP, float* __restrict__ logits,
    int* __restrict__ counts) {
  int tid = threadIdx.x;
  int w = tid >> 6, l = tid & 63;
  int lo16 = l & 15, hi4 = l >> 4;
  bf16x8 aw[4][2];
  if (PACKED) {
#pragma unroll
    for (int s = 0; s < 2; s++)
#pragma unroll
      for (int n = 0; n < 4; n++)
        aw[n][s] = __builtin_bit_cast(bf16x8, weP[(s * 4 + n) * 64 + l]);
  } else {
    for (int n = 0; n < 4; n++)
      for (int s = 0; s < 2; s++) {
        bf16x8 t;
#pragma unroll
        for (int j = 0; j < 8; j++)
          t[j] = (short)f2b(We[(s * 32 + hi4 * 8 + j) * 64 + lo16 + 16 * n]);
        aw[n][s] = t;
      }
  }
  float att4[4][4];
#pragma unroll
  for (int n = 0; n < 4; n++) {
    float4 a = *(const float4*)(att + 16 * n + hi4 * 4);
    att4[n][0] = a.x; att4[n][1] = a.y; att4[n][2] = a.z; att4[n][3] = a.w;
  }
  int wgid = blockIdx.x * 4 + w;
  for (int it = 0; it < NT; it++) {
    int e0 = (wgid * NT + it) * 16;
    int er = e0 + lo16;                       // this lane's edge (B column)
    int sj = ei[er], dj = ei[EE + er];
    bf16x8 bfr[2];
#pragma unroll
    for (int s2 = 0; s2 < 2; s2++) {
      const float4* p = (const float4*)(ea + (size_t)er * 64 + s2 * 32 + hi4 * 8);
      float4 f0 = p[0], f1 = p[1];
      uint4 u;
      u.x = pk2(f0.x, f0.y); u.y = pk2(f0.z, f0.w);
      u.z = pk2(f1.x, f1.y); u.w = pk2(f1.z, f1.w);
      bfr[s2] = __builtin_bit_cast(bf16x8, u);
    }
    f32x4 z4 = {0.f, 0.f, 0.f, 0.f};
    f32x4 acc[4] = {z4, z4, z4, z4};
#pragma unroll
    for (int s2 = 0; s2 < 2; s2++)
#pragma unroll
      for (int n = 0; n < 4; n++)
        acc[n] = __builtin_amdgcn_mfma_f32_16x16x32_bf16(aw[n][s2], bfr[s2], acc[n], 0, 0, 0);
    // D[m = We-col within tile = hi4*4+r (+16n), n = edge = lo16]
    float lg[4];
#pragma unroll
    for (int n = 0; n < 4; n++) {
      float4 gl = *(const float4*)(xl + (size_t)sj * 64 + 16 * n + hi4 * 4);
      float4 gr = *(const float4*)(xr + (size_t)dj * 64 + 16 * n + hi4 * 4);
      float gla[4] = {gl.x, gl.y, gl.z, gl.w};
      float gra[4] = {gr.x, gr.y, gr.z, gr.w};
      float s = 0.f;
#pragma unroll
      for (int r = 0; r < 4; r++) {
        float z = acc[n][r] + gla[r] + gra[r];
        z = (z >= 0.f) ? z : 0.2f * z;
        s += z * att4[n][r];
      }
      s += __shfl_xor(s, 16, 64);
      s += __shfl_xor(s, 32, 64);
      lg[n] = s;
    }
    if (hi4 == 0) {
      float4 o; o.x = lg[0]; o.y = lg[1]; o.z = lg[2]; o.w = lg[3];
      ((float4*)logits)[er] = o;
      atomicAdd(&counts[dj], 1);
    }
  }
}

// ---------- K3a/b/c: hierarchical exclusive scan of counts ----------
__global__ __launch_bounds__(256) void k_scan_sum(const int* __restrict__ counts,
                                                  int* __restrict__ bsum, int n) {
  __shared__ int red[256];
  int t = threadIdx.x;
  int idx = blockIdx.x * 256 + t;
  red[t] = (idx < n) ? counts[idx] : 0;
  __syncthreads();
  for (int off = 128; off > 0; off >>= 1) {
    if (t < off) red[t] += red[t + off];
    __syncthreads();
  }
  if (t == 0) bsum[blockIdx.x] = red[0];
}
__global__ __launch_bounds__(256) void k_scan_blk(const int* __restrict__ bsum,
                                                  int* __restrict__ boff,
                                                  int* __restrict__ offsets_end, int nb) {
  __shared__ int tmp[256];
  int t = threadIdx.x;
  int v = (t < nb) ? bsum[t] : 0;
  tmp[t] = v;
  __syncthreads();
  for (int off = 1; off < 256; off <<= 1) {
    int u = (t >= off) ? tmp[t - off] : 0;
    __syncthreads();
    tmp[t] += u;
    __syncthreads();
  }
  if (t < nb) boff[t] = tmp[t] - v;
  if (t == 255) offsets_end[0] = tmp[255];
}
__global__ __launch_bounds__(256) void k_scan_apply(const int* __restrict__ counts,
                                                    const int* __restrict__ boff,
                                                    int* __restrict__ offsets,
                                                    int* __restrict__ cursor, int n) {
  __shared__ int tmp[256];
  int t = threadIdx.x;
  int idx = blockIdx.x * 256 + t;
  int v = (idx < n) ? counts[idx] : 0;
  tmp[t] = v;
  __syncthreads();
  for (int off = 1; off < 256; off <<= 1) {
    int u = (t >= off) ? tmp[t - off] : 0;
    __syncthreads();
    tmp[t] += u;
    __syncthreads();
  }
  if (idx < n) {
    int ex = boff[blockIdx.x] + tmp[t] - v;
    offsets[idx] = ex;
    cursor[idx] = ex;
  }
}

// ---------- K4: scatter edge ids into CSR ----------
__global__ __launch_bounds__(256) void k_scatter(const int* __restrict__ ei,
                                                 int* __restrict__ cursor,
                                                 int* __restrict__ edge_of, int ne) {
  int e = blockIdx.x * blockDim.x + threadIdx.x;
  for (; e < ne; e += gridDim.x * blockDim.x) {
    int d = ei[EE + e];
    int pos = atomicAdd(&cursor[d], 1);
    edge_of[pos] = e;
  }
}

// ---------- K5: per-node online segment softmax + aggregate (+ bf16 x_out copy) ----------
__global__ __launch_bounds__(256) void k_node_agg(
    const int* __restrict__ ei, const int* __restrict__ offsets,
    const int* __restrict__ edge_of, const float* __restrict__ logits,
    const float* __restrict__ xl, const float* __restrict__ bias,
    float* __restrict__ xout, ushort* __restrict__ xb, int n) {
  int tid = threadIdx.x;
  int y = tid >> 6, t = tid & 63;
  int h = t >> 4;
  float bv = bias[t];
  for (int base = blockIdx.x * 4; base < n; base += gridDim.x * 4) {
    int i = base + y;
    if (i >= n) continue;  // wave-uniform
    int beg = offsets[i], end = offsets[i + 1];
    float m = -__builtin_inff();
    float den = 0.f, acc = 0.f;
    for (int j = beg; j < end; j++) {
      int e = edge_of[j];
      int s = ei[e];
      float lg = logits[(size_t)e * 4 + h];
      float xv = xl[(size_t)s * 64 + t];
      float mnew = fmaxf(m, lg);
      float corr = __expf(m - mnew);
      float p = __expf(lg - mnew);
      den = den * corr + p;
      acc = acc * corr + p * xv;
      m = mnew;
    }
    float o = acc / (den + 1e-16f) + bv;
    xout[(size_t)i * 64 + t] = o;
    if (xb) xb[(size_t)i * 64 + t] = f2b(o);
  }
}

// ---------- K6: edge MLP via MFMA, in-register A-frags, coalesced epilogue ----------
template <bool PACKED>
__global__ __launch_bounds__(256) void k_edge_mlp(
    const float* __restrict__ ea, const int* __restrict__ ei,
    const float* __restrict__ xoutf, const ushort* __restrict__ xb,
    const float* __restrict__ lng, const float* __restrict__ lnb,
    const float* __restrict__ Wm, const uint4* __restrict__ wmP,
    const float* __restrict__ bm, float* __restrict__ eout) {
  __shared__ float sT[4][16 * 68];   // per-wave transpose buffer (stride 68: 2-way banks = free)
  int tid = threadIdx.x;
  int w = tid >> 6, l = tid & 63;
  int lo16 = l & 15, hi4 = l >> 4;
  bf16x8 bwm[4][4];
  if (PACKED) {
#pragma unroll
    for (int s2 = 0; s2 < 4; s2++)
#pragma unroll
      for (int n = 0; n < 4; n++)
        bwm[n][s2] = __builtin_bit_cast(bf16x8, wmP[(s2 * 4 + n) * 64 + l]);
  } else {
    for (int n = 0; n < 4; n++)
      for (int s2 = 0; s2 < 4; s2++) {
        bf16x8 t;
#pragma unroll
        for (int j = 0; j < 8; j++)
          t[j] = (short)f2b(Wm[(s2 * 32 + hi4 * 8 + j) * 64 + lo16 + 16 * n]);
        bwm[n][s2] = t;
      }
  }
  float bmv[4];
#pragma unroll
  for (int n = 0; n < 4; n++) bmv[n] = bm[lo16 + 16 * n];

  int wgid = blockIdx.x * 4 + w;
  int m2 = l >> 2, q2 = l & 3;   // epilogue row/quarter
  for (int it = 0; it < NT; it++) {
    int e0 = (wgid * NT + it) * 16;
    int er = e0 + lo16;                         // this lane's edge (A row)
    int sj = ei[er], dj = ei[EE + er];
    // gather 4 x 8-col chunks of the two x_out rows: k = s2*32 + hi4*8 + j
    float v[4][8];
    if (PACKED) {
      up8(*(const uint4*)(xb + (size_t)sj * 64 + hi4 * 8), v[0]);
      up8(*(const uint4*)(xb + (size_t)sj * 64 + 32 + hi4 * 8), v[1]);
      up8(*(const uint4*)(xb + (size_t)dj * 64 + hi4 * 8), v[2]);
      up8(*(const uint4*)(xb + (size_t)dj * 64 + 32 + hi4 * 8), v[3]);
    } else {
#pragma unroll
      for (int s2 = 0; s2 < 4; s2++) {
        const float* src = (s2 < 2) ? (xoutf + (size_t)sj * 64 + (s2 & 1) * 32 + hi4 * 8)
                                    : (xoutf + (size_t)dj * 64 + (s2 & 1) * 32 + hi4 * 8);
        float4 a = *(const float4*)src;
        float4 b = *(const float4*)(src + 4);
        v[s2][0] = a.x; v[s2][1] = a.y; v[s2][2] = a.z; v[s2][3] = a.w;
        v[s2][4] = b.x; v[s2][5] = b.y; v[s2][6] = b.z; v[s2][7] = b.w;
      }
    }
    // LN stats over the 128-concat (quad-reduce across hi4)
    float sm = 0.f, sq = 0.f;
#pragma unroll
    for (int s2 = 0; s2 < 4; s2++)
#pragma unroll
      for (int j = 0; j < 8; j++) { sm += v[s2][j]; sq += v[s2][j] * v[s2][j]; }
    sm += __shfl_xor(sm, 16, 64); sm += __shfl_xor(sm, 32, 64);
    sq += __shfl_xor(sq, 16, 64); sq += __shfl_xor(sq, 32, 64);
    float mean = sm * (1.f / 128.f);
    float var = sq * (1.f / 128.f) - mean * mean;
    float rs = rsqrtf(var + 1e-5f);
    // h = relu(LN) -> bf16 A-frags in registers
    f32x4 zz = {bmv[0], bmv[0], bmv[0], bmv[0]};
    f32x4 acc[4];
#pragma unroll
    for (int n = 0; n < 4; n++) {
      f32x4 c = {bmv[n], bmv[n], bmv[n], bmv[n]};
      acc[n] = c;
    }
    (void)zz;
#pragma unroll
    for (int s2 = 0; s2 < 4; s2++) {
      float4 ga = *(const float4*)(lng + s2 * 32 + hi4 * 8);
      float4 gb = *(const float4*)(lng + s2 * 32 + hi4 * 8 + 4);
      float4 ba = *(const float4*)(lnb + s2 * 32 + hi4 * 8);
      float4 bb = *(const float4*)(lnb + s2 * 32 + hi4 * 8 + 4);
      float g8[8] = {ga.x, ga.y, ga.z, ga.w, gb.x, gb.y, gb.z, gb.w};
      float b8[8] = {ba.x, ba.y, ba.z, ba.w, bb.x, bb.y, bb.z, bb.w};
      float h8[8];
#pragma unroll
      for (int j = 0; j < 8; j++)
        h8[j] = fmaxf(fmaf((v[s2][j] - mean) * rs, g8[j], b8[j]), 0.f);
      uint4 u;
      u.x = pk2(h8[0], h8[1]); u.y = pk2(h8[2], h8[3]);
      u.z = pk2(h8[4], h8[5]); u.w = pk2(h8[6], h8[7]);
      bf16x8 afr = __builtin_bit_cast(bf16x8, u);
#pragma unroll
      for (int n = 0; n < 4; n++)
        acc[n] = __builtin_amdgcn_mfma_f32_16x16x32_bf16(afr, bwm[n][s2], acc[n], 0, 0, 0);
    }
    // transpose via wave-local LDS: D[row = hi4*4+r (edge), col = lo16+16n]
#pragma unroll
    for (int n = 0; n < 4; n++)
#pragma unroll
      for (int r = 0; r < 4; r++)
        sT[w][(hi4 * 4 + r) * 68 + lo16 + 16 * n] = acc[n][r];
    // stream out: lane covers edge m2, cols q2*16..+15 (contiguous 64B/lane, 4KB/wave)
#pragma unroll
    for (int c = 0; c < 4; c++) {
      float4 t4 = *(float4*)&sT[w][m2 * 68 + q2 * 16 + 4 * c];
      size_t off = (size_t)(e0 + m2) * 64 + q2 * 16 + 4 * c;
      float4 r4 = *(const float4*)(ea + off);
      float4 o;
      o.x = r4.x + t4.x; o.y = r4.y + t4.y; o.z = r4.z + t4.z; o.w = r4.w + t4.w;
      *(float4*)(eout + off) = o;
    }
  }
}

extern "C" void kernel_launch(void* const* d_in, const int* in_sizes, int n_in,
                              void* d_out, int out_size, void* d_ws, size_t ws_size,
                              hipStream_t stream) {
  const float* x   = (const float*)d_in[0];
  const int*   ei  = (const int*)d_in[1];
  const float* ea  = (const float*)d_in[2];
  const float* Wl  = (const float*)d_in[3];
  const float* Wr  = (const float*)d_in[4];
  const float* We  = (const float*)d_in[5];
  const float* att = (const float*)d_in[6];
  const float* cb  = (const float*)d_in[7];
  const float* lng = (const float*)d_in[8];
  const float* lnb = (const float*)d_in[9];
  const float* Wm  = (const float*)d_in[10];
  const float* bm  = (const float*)d_in[11];

  float* out  = (float*)d_out;
  float* xout = out;                       // [N,64]
  float* eout = out + (size_t)NN * 64;     // [E,64]

  const int nb = (NN + 255) / 256;         // 196 scan blocks

  // ws layout: packs first (16B aligned), then floats, then ints
  size_t packBytes = (size_t)(1024 + 512) * 16;                    // wmP + weP
  size_t fWords    = (size_t)NN * 64 * 2 + (size_t)EE * 4;         // xl, xr, logits
  size_t xbWords   = (size_t)NN * 64 / 2;                          // bf16 x_out
  size_t intWords  = (size_t)NN * 3 + 1 + (size_t)EE + 512;        // counts/off/cur/edge_of/bsum/boff
  size_t needBytes = packBytes + (fWords + xbWords + intWords) * 4;
  bool useWs = (ws_size >= needBytes);

  uint4*  wmP = useWs ? (uint4*)d_ws : nullptr;
  uint4*  weP = useWs ? wmP + 1024 : nullptr;
  float*  fbase = useWs ? (float*)((char*)d_ws + packBytes) : eout;

  float*  xl      = fbase;
  float*  xr      = xl + (size_t)NN * 64;
  float*  logits  = xr + (size_t)NN * 64;
  ushort* xb      = useWs ? (ushort*)(logits + (size_t)EE * 4) : nullptr;
  int*    counts  = useWs ? (int*)(xb + (size_t)NN * 64)
                          : (int*)(logits + (size_t)EE * 4);
  int*    offsets = counts + NN;
  int*    cursor  = offsets + NN + 1;
  int*    edge_of = cursor + NN;
  int*    bsum    = edge_of + EE;
  int*    boff    = bsum + 256;

  hipMemsetAsync(counts, 0, NN * sizeof(int), stream);
  if (useWs) k_prep<<<6, 256, 0, stream>>>(Wm, We, wmP, weP);
  k_node_linear<<<(NN + 255) / 256, 256, 0, stream>>>(x, Wl, Wr, xl, xr, NN);
  if (useWs)
    k_edge_logits<true><<<1250, 256, 0, stream>>>(ea, ei, We, att, xl, xr, weP, logits, counts);
  else
    k_edge_logits<false><<<1250, 256, 0, stream>>>(ea, ei, We, att, xl, xr, nullptr, logits, counts);
  k_scan_sum<<<nb, 256, 0, stream>>>(counts, bsum, NN);
  k_scan_blk<<<1, 256, 0, stream>>>(bsum, boff, offsets + NN, nb);
  k_scan_apply<<<nb, 256, 0, stream>>>(counts, boff, offsets, cursor, NN);
  k_scatter<<<1024, 256, 0, stream>>>(ei, cursor, edge_of, EE);
  k_node_agg<<<2048, 256, 0, stream>>>(ei, offsets, edge_of, logits, xl, cb, xout, xb, NN);
  if (useWs)
    k_edge_mlp<true><<<1250, 256, 0, stream>>>(ea, ei, xout, xb, lng, lnb, Wm, wmP, bm, eout);
  else
    k_edge_mlp<false><<<1250, 256, 0, stream>>>(ea, ei, xout, nullptr, lng, lnb, Wm, nullptr, bm, eout);
}

// Round 6
// 505.332 us; speedup vs baseline: 2.7729x; 1.0570x over previous
//
#include <hip/hip_runtime.h>
#include <cstdint>
#include <cstddef>

#define NN 50000
#define EE 800000
#define NT 10   // 16-edge tiles per wave; 1250 blocks * 4 waves * NT * 16 == EE

typedef short bf16x8 __attribute__((ext_vector_type(8)));
typedef float f32x4 __attribute__((ext_vector_type(4)));
typedef float fx4 __attribute__((ext_vector_type(4)));

static __device__ __forceinline__ ushort f2b(float f) {
  uint u = __builtin_bit_cast(uint, f);
  u += 0x7FFFu + ((u >> 16) & 1u);
  return (ushort)(u >> 16);
}
static __device__ __forceinline__ float b2f(ushort h) {
  return __builtin_bit_cast(float, ((uint)h) << 16);
}
static __device__ __forceinline__ uint pk2(float a, float b) {
  return (uint)f2b(a) | (((uint)f2b(b)) << 16);
}
static __device__ __forceinline__ void up8(uint4 u, float* o) {
  o[0] = b2f((ushort)(u.x & 0xFFFF)); o[1] = b2f((ushort)(u.x >> 16));
  o[2] = b2f((ushort)(u.y & 0xFFFF)); o[3] = b2f((ushort)(u.y >> 16));
  o[4] = b2f((ushort)(u.z & 0xFFFF)); o[5] = b2f((ushort)(u.z >> 16));
  o[6] = b2f((ushort)(u.w & 0xFFFF)); o[7] = b2f((ushort)(u.w >> 16));
}

// ---------- K0: pack Wm/We into MFMA frag-ordered uint4 tables ----------
__global__ __launch_bounds__(256) void k_prep(const float* __restrict__ Wm,
                                              const float* __restrict__ We,
                                              uint4* __restrict__ wmP,
                                              uint4* __restrict__ weP) {
  int idx = blockIdx.x * 256 + threadIdx.x;  // 6 blocks * 256 = 1536
  if (idx < 1024) {
    int s2 = idx >> 8, n = (idx >> 6) & 3, lane = idx & 63;
    int lo = lane & 15, hi = lane >> 4;
    ushort h[8];
#pragma unroll
    for (int j = 0; j < 8; j++) h[j] = f2b(Wm[(s2 * 32 + hi * 8 + j) * 64 + lo + 16 * n]);
    uint4 u;
    u.x = (uint)h[0] | ((uint)h[1] << 16); u.y = (uint)h[2] | ((uint)h[3] << 16);
    u.z = (uint)h[4] | ((uint)h[5] << 16); u.w = (uint)h[6] | ((uint)h[7] << 16);
    wmP[idx] = u;
  } else if (idx < 1536) {
    int k = idx - 1024;
    int s = k >> 8, n = (k >> 6) & 3, lane = k & 63;
    int lo = lane & 15, hi = lane >> 4;
    ushort h[8];
#pragma unroll
    for (int j = 0; j < 8; j++) h[j] = f2b(We[(s * 32 + hi * 8 + j) * 64 + lo + 16 * n]);
    uint4 u;
    u.x = (uint)h[0] | ((uint)h[1] << 16); u.y = (uint)h[2] | ((uint)h[3] << 16);
    u.z = (uint)h[4] | ((uint)h[5] << 16); u.w = (uint)h[6] | ((uint)h[7] << 16);
    weP[k] = u;
  }
}

// ---------- K1: xl = x@Wl, xr = x@Wr ----------
__global__ __launch_bounds__(256, 3) void k_node_linear(
    const float* __restrict__ x, const float* __restrict__ Wl,
    const float* __restrict__ Wr, float* __restrict__ xl,
    float* __restrict__ xr, int n) {
  int i = blockIdx.x * 256 + threadIdx.x;
  if (i >= n) return;
  const float4* px = (const float4*)(x + (size_t)i * 64);
  float accl[64], accr[64];
#pragma unroll
  for (int c = 0; c < 64; c++) { accl[c] = 0.f; accr[c] = 0.f; }
  for (int kq = 0; kq < 16; kq++) {
    float4 v = px[kq];
#pragma unroll
    for (int j = 0; j < 4; j++) {
      float xv = (j == 0) ? v.x : (j == 1) ? v.y : (j == 2) ? v.z : v.w;
      const float* wl = Wl + (kq * 4 + j) * 64;
      const float* wr = Wr + (kq * 4 + j) * 64;
#pragma unroll
      for (int c = 0; c < 64; c++) {
        accl[c] = fmaf(xv, wl[c], accl[c]);
        accr[c] = fmaf(xv, wr[c], accr[c]);
      }
    }
  }
  float4* pl = (float4*)(xl + (size_t)i * 64);
  float4* pr = (float4*)(xr + (size_t)i * 64);
#pragma unroll
  for (int q = 0; q < 16; q++) {
    float4 a, b;
    a.x = accl[4 * q]; a.y = accl[4 * q + 1]; a.z = accl[4 * q + 2]; a.w = accl[4 * q + 3];
    b.x = accr[4 * q]; b.y = accr[4 * q + 1]; b.z = accr[4 * q + 2]; b.w = accr[4 * q + 3];
    pl[q] = a; pr[q] = b;
  }
}

// ---------- K2: logits via MFMA, pipelined (swapped operands: D[col][edge]) ----------
template <bool PACKED>
__global__ __launch_bounds__(256) void k_edge_logits(
    const float* __restrict__ ea, const int* __restrict__ ei,
    const float* __restrict__ We, const float* __restrict__ att,
    const float* __restrict__ xl, const float* __restrict__ xr,
    const uint4* __restrict__ weP, float* __restrict__ logits,
    int* __restrict__ counts) {
  int tid = threadIdx.x;
  int w = tid >> 6, l = tid & 63;
  int lo16 = l & 15, hi4 = l >> 4;
  bf16x8 aw[4][2];
  if (PACKED) {
#pragma unroll
    for (int s = 0; s < 2; s++)
#pragma unroll
      for (int n = 0; n < 4; n++)
        aw[n][s] = __builtin_bit_cast(bf16x8, weP[(s * 4 + n) * 64 + l]);
  } else {
    for (int n = 0; n < 4; n++)
      for (int s = 0; s < 2; s++) {
        bf16x8 t;
#pragma unroll
        for (int j = 0; j < 8; j++)
          t[j] = (short)f2b(We[(s * 32 + hi4 * 8 + j) * 64 + lo16 + 16 * n]);
        aw[n][s] = t;
      }
  }
  float att4[4][4];
#pragma unroll
  for (int n = 0; n < 4; n++) {
    float4 a = *(const float4*)(att + 16 * n + hi4 * 4);
    att4[n][0] = a.x; att4[n][1] = a.y; att4[n][2] = a.z; att4[n][3] = a.w;
  }
  int wgid = blockIdx.x * 4 + w;
  int ebase = wgid * NT * 16;
  // prologue: tile-0 indices
  int sj = ei[ebase + lo16], dj = ei[EE + ebase + lo16];
  for (int it = 0; it < NT; it++) {
    int er = ebase + it * 16 + lo16;
    int djc = dj;
    // gathers for this tile issue NOW (indices arrived during prev tile)
    fx4 gl[4], gr[4];
#pragma unroll
    for (int n = 0; n < 4; n++) {
      gl[n] = *(const fx4*)(xl + (size_t)sj * 64 + 16 * n + hi4 * 4);
      gr[n] = *(const fx4*)(xr + (size_t)dj * 64 + 16 * n + hi4 * 4);
    }
    // prefetch next tile's indices (latency hidden by pack+MFMA below)
    if (it + 1 < NT) {
      sj = ei[er + 16];
      dj = ei[EE + er + 16];
    }
    // ea -> bf16 B-frags (streaming, nontemporal)
    bf16x8 bfr[2];
#pragma unroll
    for (int s2 = 0; s2 < 2; s2++) {
      const fx4* p = (const fx4*)(ea + (size_t)er * 64 + s2 * 32 + hi4 * 8);
      fx4 f0 = __builtin_nontemporal_load(p);
      fx4 f1 = __builtin_nontemporal_load(p + 1);
      uint4 u;
      u.x = pk2(f0[0], f0[1]); u.y = pk2(f0[2], f0[3]);
      u.z = pk2(f1[0], f1[1]); u.w = pk2(f1[2], f1[3]);
      bfr[s2] = __builtin_bit_cast(bf16x8, u);
    }
    f32x4 z4 = {0.f, 0.f, 0.f, 0.f};
    f32x4 acc[4] = {z4, z4, z4, z4};
#pragma unroll
    for (int s2 = 0; s2 < 2; s2++)
#pragma unroll
      for (int n = 0; n < 4; n++)
        acc[n] = __builtin_amdgcn_mfma_f32_16x16x32_bf16(aw[n][s2], bfr[s2], acc[n], 0, 0, 0);
    // D[m = We-col = hi4*4+r (+16n), n = edge = lo16]
    float lg[4];
#pragma unroll
    for (int n = 0; n < 4; n++) {
      float s = 0.f;
#pragma unroll
      for (int r = 0; r < 4; r++) {
        float z = acc[n][r] + gl[n][r] + gr[n][r];
        z = (z >= 0.f) ? z : 0.2f * z;
        s += z * att4[n][r];
      }
      s += __shfl_xor(s, 16, 64);
      s += __shfl_xor(s, 32, 64);
      lg[n] = s;
    }
    if (hi4 == 0) {
      fx4 o = {lg[0], lg[1], lg[2], lg[3]};
      __builtin_nontemporal_store(o, (fx4*)logits + er);
      atomicAdd(&counts[djc], 1);
    }
  }
}

// ---------- K3a/b/c: hierarchical exclusive scan of counts ----------
__global__ __launch_bounds__(256) void k_scan_sum(const int* __restrict__ counts,
                                                  int* __restrict__ bsum, int n) {
  __shared__ int red[256];
  int t = threadIdx.x;
  int idx = blockIdx.x * 256 + t;
  red[t] = (idx < n) ? counts[idx] : 0;
  __syncthreads();
  for (int off = 128; off > 0; off >>= 1) {
    if (t < off) red[t] += red[t + off];
    __syncthreads();
  }
  if (t == 0) bsum[blockIdx.x] = red[0];
}
__global__ __launch_bounds__(256) void k_scan_blk(const int* __restrict__ bsum,
                                                  int* __restrict__ boff,
                                                  int* __restrict__ offsets_end, int nb) {
  __shared__ int tmp[256];
  int t = threadIdx.x;
  int v = (t < nb) ? bsum[t] : 0;
  tmp[t] = v;
  __syncthreads();
  for (int off = 1; off < 256; off <<= 1) {
    int u = (t >= off) ? tmp[t - off] : 0;
    __syncthreads();
    tmp[t] += u;
    __syncthreads();
  }
  if (t < nb) boff[t] = tmp[t] - v;
  if (t == 255) offsets_end[0] = tmp[255];
}
__global__ __launch_bounds__(256) void k_scan_apply(const int* __restrict__ counts,
                                                    const int* __restrict__ boff,
                                                    int* __restrict__ offsets,
                                                    int* __restrict__ cursor, int n) {
  __shared__ int tmp[256];
  int t = threadIdx.x;
  int idx = blockIdx.x * 256 + t;
  int v = (idx < n) ? counts[idx] : 0;
  tmp[t] = v;
  __syncthreads();
  for (int off = 1; off < 256; off <<= 1) {
    int u = (t >= off) ? tmp[t - off] : 0;
    __syncthreads();
    tmp[t] += u;
    __syncthreads();
  }
  if (idx < n) {
    int ex = boff[blockIdx.x] + tmp[t] - v;
    offsets[idx] = ex;
    cursor[idx] = ex;
  }
}

// ---------- K4: scatter edge ids into CSR ----------
__global__ __launch_bounds__(256) void k_scatter(const int* __restrict__ ei,
                                                 int* __restrict__ cursor,
                                                 int* __restrict__ edge_of, int ne) {
  int e = blockIdx.x * blockDim.x + threadIdx.x;
  for (; e < ne; e += gridDim.x * blockDim.x) {
    int d = ei[EE + e];
    int pos = atomicAdd(&cursor[d], 1);
    edge_of[pos] = e;
  }
}

// ---------- K5: segment softmax + aggregate, lane-parallel edge meta ----------
__global__ __launch_bounds__(256) void k_node_agg(
    const int* __restrict__ ei, const int* __restrict__ offsets,
    const int* __restrict__ edge_of, const float* __restrict__ logits,
    const float* __restrict__ xl, const float* __restrict__ bias,
    float* __restrict__ xout, ushort* __restrict__ xb, int n) {
  int tid = threadIdx.x;
  int y = tid >> 6, l = tid & 63;
  int h = l >> 4;
  float bv = bias[l];
  const float NINF = -__builtin_inff();
  for (int base = blockIdx.x * 4; base < n; base += gridDim.x * 4) {
    int i = base + y;
    if (i >= n) continue;  // wave-uniform
    int beg = offsets[i], end = offsets[i + 1];
    float m = NINF, den = 0.f, acc = 0.f;
    for (int c0 = beg; c0 < end; c0 += 64) {
      int cnt = min(64, end - c0);
      // phase A: lane l <-> edge l of this chunk (parallel meta loads)
      int e_l = 0, s_l = 0;
      fx4 lg4 = {NINF, NINF, NINF, NINF};
      if (l < cnt) {
        e_l = edge_of[c0 + l];
        s_l = ei[e_l];
        lg4 = ((const fx4*)logits)[e_l];
      }
      // per-head max over chunk (wave reduce)
      float mh[4];
#pragma unroll
      for (int hh = 0; hh < 4; hh++) {
        float v = lg4[hh];
#pragma unroll
        for (int off = 32; off > 0; off >>= 1) v = fmaxf(v, __shfl_xor(v, off, 64));
        mh[hh] = v;
      }
      float mnew = fmaxf(m, mh[h]);
      float corr = __expf(m - mnew);   // 0 when m was -inf
      den *= corr; acc *= corr; m = mnew;
      // phase B: 4 edges per step; addresses via shfl (no memory round trip)
      for (int j = 0; j < cnt; j += 4) {
        int nb4 = min(4, cnt - j);
        float xv[4], lgv[4];
#pragma unroll
        for (int u = 0; u < 4; u++) {
          if (u < nb4) {
            int su = __shfl(s_l, j + u, 64);
            int eu = __shfl(e_l, j + u, 64);
            xv[u] = xl[(size_t)su * 64 + l];
            lgv[u] = logits[(size_t)eu * 4 + h];
          }
        }
#pragma unroll
        for (int u = 0; u < 4; u++) {
          if (u < nb4) {
            float p = __expf(lgv[u] - m);
            den += p;
            acc = fmaf(p, xv[u], acc);
          }
        }
      }
    }
    float o = acc / (den + 1e-16f) + bv;
    __builtin_nontemporal_store(o, xout + (size_t)i * 64 + l);
    if (xb) xb[(size_t)i * 64 + l] = f2b(o);
  }
}

// ---------- K6: edge MLP via MFMA, software-pipelined ----------
template <bool PACKED>
__global__ __launch_bounds__(256) void k_edge_mlp(
    const float* __restrict__ ea, const int* __restrict__ ei,
    const float* __restrict__ xoutf, const ushort* __restrict__ xb,
    const float* __restrict__ lng, const float* __restrict__ lnb,
    const float* __restrict__ Wm, const uint4* __restrict__ wmP,
    const float* __restrict__ bm, float* __restrict__ eout) {
  __shared__ float sT[4][16 * 68];   // per-wave transpose buffer
  int tid = threadIdx.x;
  int w = tid >> 6, l = tid & 63;
  int lo16 = l & 15, hi4 = l >> 4;
  bf16x8 bwm[4][4];
  if (PACKED) {
#pragma unroll
    for (int s2 = 0; s2 < 4; s2++)
#pragma unroll
      for (int n = 0; n < 4; n++)
        bwm[n][s2] = __builtin_bit_cast(bf16x8, wmP[(s2 * 4 + n) * 64 + l]);
  } else {
    for (int n = 0; n < 4; n++)
      for (int s2 = 0; s2 < 4; s2++) {
        bf16x8 t;
#pragma unroll
        for (int j = 0; j < 8; j++)
          t[j] = (short)f2b(Wm[(s2 * 32 + hi4 * 8 + j) * 64 + lo16 + 16 * n]);
        bwm[n][s2] = t;
      }
  }
  float bmv[4];
#pragma unroll
  for (int n = 0; n < 4; n++) bmv[n] = bm[lo16 + 16 * n];

  int wgid = blockIdx.x * 4 + w;
  int ebase = wgid * NT * 16;
  int m2 = l >> 2, q2 = l & 3;   // epilogue row/quarter

  // prologue: tile-0 indices + gathers
  int sj = ei[ebase + lo16], dj = ei[EE + ebase + lo16];
  uint4 pf0, pf1, pf2, pf3;
  float4 pg[4];  // f32 fallback
  if (PACKED) {
    pf0 = *(const uint4*)(xb + (size_t)sj * 64 + hi4 * 8);
    pf1 = *(const uint4*)(xb + (size_t)sj * 64 + 32 + hi4 * 8);
    pf2 = *(const uint4*)(xb + (size_t)dj * 64 + hi4 * 8);
    pf3 = *(const uint4*)(xb + (size_t)dj * 64 + 32 + hi4 * 8);
  }
  for (int it = 0; it < NT; it++) {
    int e0 = ebase + it * 16;
    // unpack current gathers
    float v[4][8];
    if (PACKED) {
      up8(pf0, v[0]); up8(pf1, v[1]); up8(pf2, v[2]); up8(pf3, v[3]);
    } else {
#pragma unroll
      for (int s2 = 0; s2 < 4; s2++) {
        const float* src = (s2 < 2) ? (xoutf + (size_t)sj * 64 + (s2 & 1) * 32 + hi4 * 8)
                                    : (xoutf + (size_t)dj * 64 + (s2 & 1) * 32 + hi4 * 8);
        float4 a = *(const float4*)src;
        float4 b = *(const float4*)(src + 4);
        v[s2][0] = a.x; v[s2][1] = a.y; v[s2][2] = a.z; v[s2][3] = a.w;
        v[s2][4] = b.x; v[s2][5] = b.y; v[s2][6] = b.z; v[s2][7] = b.w;
      }
      (void)pg;
    }
    // prefetch next tile's indices (hidden under LN+MFMA)
    int sjn = 0, djn = 0;
    if (it + 1 < NT) {
      sjn = ei[e0 + 16 + lo16];
      djn = ei[EE + e0 + 16 + lo16];
    }
    // LN stats (quad-reduce across hi4 groups)
    float sm = 0.f, sq = 0.f;
#pragma unroll
    for (int s2 = 0; s2 < 4; s2++)
#pragma unroll
      for (int j = 0; j < 8; j++) { sm += v[s2][j]; sq += v[s2][j] * v[s2][j]; }
    sm += __shfl_xor(sm, 16, 64); sm += __shfl_xor(sm, 32, 64);
    sq += __shfl_xor(sq, 16, 64); sq += __shfl_xor(sq, 32, 64);
    float mean = sm * (1.f / 128.f);
    float var = sq * (1.f / 128.f) - mean * mean;
    float rs = rsqrtf(var + 1e-5f);
    // normalize -> bf16 A-frags -> MFMA
    f32x4 acc[4];
#pragma unroll
    for (int n = 0; n < 4; n++) {
      f32x4 c = {bmv[n], bmv[n], bmv[n], bmv[n]};
      acc[n] = c;
    }
#pragma unroll
    for (int s2 = 0; s2 < 4; s2++) {
      float4 ga = *(const float4*)(lng + s2 * 32 + hi4 * 8);
      float4 gb = *(const float4*)(lng + s2 * 32 + hi4 * 8 + 4);
      float4 ba = *(const float4*)(lnb + s2 * 32 + hi4 * 8);
      float4 bb = *(const float4*)(lnb + s2 * 32 + hi4 * 8 + 4);
      float g8[8] = {ga.x, ga.y, ga.z, ga.w, gb.x, gb.y, gb.z, gb.w};
      float b8[8] = {ba.x, ba.y, ba.z, ba.w, bb.x, bb.y, bb.z, bb.w};
      float h8[8];
#pragma unroll
      for (int j = 0; j < 8; j++)
        h8[j] = fmaxf(fmaf((v[s2][j] - mean) * rs, g8[j], b8[j]), 0.f);
      uint4 u;
      u.x = pk2(h8[0], h8[1]); u.y = pk2(h8[2], h8[3]);
      u.z = pk2(h8[4], h8[5]); u.w = pk2(h8[6], h8[7]);
      bf16x8 afr = __builtin_bit_cast(bf16x8, u);
#pragma unroll
      for (int n = 0; n < 4; n++)
        acc[n] = __builtin_amdgcn_mfma_f32_16x16x32_bf16(afr, bwm[n][s2], acc[n], 0, 0, 0);
    }
    // issue next tile's gathers (overlap with epilogue's HBM traffic)
    if (it + 1 < NT) {
      if (PACKED) {
        pf0 = *(const uint4*)(xb + (size_t)sjn * 64 + hi4 * 8);
        pf1 = *(const uint4*)(xb + (size_t)sjn * 64 + 32 + hi4 * 8);
        pf2 = *(const uint4*)(xb + (size_t)djn * 64 + hi4 * 8);
        pf3 = *(const uint4*)(xb + (size_t)djn * 64 + 32 + hi4 * 8);
      }
      sj = sjn; dj = djn;
    }
    // transpose via wave-local LDS: D[row = hi4*4+r (edge), col = lo16+16n]
#pragma unroll
    for (int n = 0; n < 4; n++)
#pragma unroll
      for (int r = 0; r < 4; r++)
        sT[w][(hi4 * 4 + r) * 68 + lo16 + 16 * n] = acc[n][r];
    // epilogue: coalesced nt ea-read + nt eout-write
#pragma unroll
    for (int c = 0; c < 4; c++) {
      fx4 t4 = *(const fx4*)&sT[w][m2 * 68 + q2 * 16 + 4 * c];
      size_t off = (size_t)(e0 + m2) * 64 + q2 * 16 + 4 * c;
      fx4 r4 = __builtin_nontemporal_load((const fx4*)(ea + off));
      fx4 o = r4 + t4;
      __builtin_nontemporal_store(o, (fx4*)(eout + off));
    }
  }
}

extern "C" void kernel_launch(void* const* d_in, const int* in_sizes, int n_in,
                              void* d_out, int out_size, void* d_ws, size_t ws_size,
                              hipStream_t stream) {
  const float* x   = (const float*)d_in[0];
  const int*   ei  = (const int*)d_in[1];
  const float* ea  = (const float*)d_in[2];
  const float* Wl  = (const float*)d_in[3];
  const float* Wr  = (const float*)d_in[4];
  const float* We  = (const float*)d_in[5];
  const float* att = (const float*)d_in[6];
  const float* cb  = (const float*)d_in[7];
  const float* lng = (const float*)d_in[8];
  const float* lnb = (const float*)d_in[9];
  const float* Wm  = (const float*)d_in[10];
  const float* bm  = (const float*)d_in[11];

  float* out  = (float*)d_out;
  float* xout = out;                       // [N,64]
  float* eout = out + (size_t)NN * 64;     // [E,64]

  const int nb = (NN + 255) / 256;         // 196 scan blocks

  size_t packBytes = (size_t)(1024 + 512) * 16;                    // wmP + weP
  size_t fWords    = (size_t)NN * 64 * 2 + (size_t)EE * 4;         // xl, xr, logits
  size_t xbWords   = (size_t)NN * 64 / 2;                          // bf16 x_out
  size_t intWords  = (size_t)NN * 3 + 1 + (size_t)EE + 512;
  size_t needBytes = packBytes + (fWords + xbWords + intWords) * 4;
  bool useWs = (ws_size >= needBytes);

  uint4*  wmP = useWs ? (uint4*)d_ws : nullptr;
  uint4*  weP = useWs ? wmP + 1024 : nullptr;
  float*  fbase = useWs ? (float*)((char*)d_ws + packBytes) : eout;

  float*  xl      = fbase;
  float*  xr      = xl + (size_t)NN * 64;
  float*  logits  = xr + (size_t)NN * 64;
  ushort* xb      = useWs ? (ushort*)(logits + (size_t)EE * 4) : nullptr;
  int*    counts  = useWs ? (int*)(xb + (size_t)NN * 64)
                          : (int*)(logits + (size_t)EE * 4);
  int*    offsets = counts + NN;
  int*    cursor  = offsets + NN + 1;
  int*    edge_of = cursor + NN;
  int*    bsum    = edge_of + EE;
  int*    boff    = bsum + 256;

  hipMemsetAsync(counts, 0, NN * sizeof(int), stream);
  if (useWs) k_prep<<<6, 256, 0, stream>>>(Wm, We, wmP, weP);
  k_node_linear<<<(NN + 255) / 256, 256, 0, stream>>>(x, Wl, Wr, xl, xr, NN);
  if (useWs)
    k_edge_logits<true><<<1250, 256, 0, stream>>>(ea, ei, We, att, xl, xr, weP, logits, counts);
  else
    k_edge_logits<false><<<1250, 256, 0, stream>>>(ea, ei, We, att, xl, xr, nullptr, logits, counts);
  k_scan_sum<<<nb, 256, 0, stream>>>(counts, bsum, NN);
  k_scan_blk<<<1, 256, 0, stream>>>(bsum, boff, offsets + NN, nb);
  k_scan_apply<<<nb, 256, 0, stream>>>(counts, boff, offsets, cursor, NN);
  k_scatter<<<1024, 256, 0, stream>>>(ei, cursor, edge_of, EE);
  k_node_agg<<<2048, 256, 0, stream>>>(ei, offsets, edge_of, logits, xl, cb, xout, xb, NN);
  if (useWs)
    k_edge_mlp<true><<<1250, 256, 0, stream>>>(ea, ei, xout, xb, lng, lnb, Wm, wmP, bm, eout);
  else
    k_edge_mlp<false><<<1250, 256, 0, stream>>>(ea, ei, xout, nullptr, lng, lnb, Wm, nullptr, bm, eout);
}

// Round 7
// 446.172 us; speedup vs baseline: 3.1406x; 1.1326x over previous
//
#include <hip/hip_runtime.h>
#include <cstdint>
#include <cstddef>

#define NN 50000
#define EE 800000
#define NT 5   // 16-edge tiles per wave; 2500 blocks * 4 waves * NT * 16 == EE

typedef short bf16x8 __attribute__((ext_vector_type(8)));
typedef float f32x4 __attribute__((ext_vector_type(4)));
typedef float fx4 __attribute__((ext_vector_type(4)));

static __device__ __forceinline__ ushort f2b(float f) {
  uint u = __builtin_bit_cast(uint, f);
  u += 0x7FFFu + ((u >> 16) & 1u);
  return (ushort)(u >> 16);
}
static __device__ __forceinline__ float b2f(ushort h) {
  return __builtin_bit_cast(float, ((uint)h) << 16);
}
static __device__ __forceinline__ uint pk2(float a, float b) {
  return (uint)f2b(a) | (((uint)f2b(b)) << 16);
}
static __device__ __forceinline__ void up8(uint4 u, float* o) {
  o[0] = b2f((ushort)(u.x & 0xFFFF)); o[1] = b2f((ushort)(u.x >> 16));
  o[2] = b2f((ushort)(u.y & 0xFFFF)); o[3] = b2f((ushort)(u.y >> 16));
  o[4] = b2f((ushort)(u.z & 0xFFFF)); o[5] = b2f((ushort)(u.z >> 16));
  o[6] = b2f((ushort)(u.w & 0xFFFF)); o[7] = b2f((ushort)(u.w >> 16));
}

// ---------- K0: pack Wm/We into MFMA frag-ordered uint4 tables ----------
__global__ __launch_bounds__(256) void k_prep(const float* __restrict__ Wm,
                                              const float* __restrict__ We,
                                              uint4* __restrict__ wmP,
                                              uint4* __restrict__ weP) {
  int idx = blockIdx.x * 256 + threadIdx.x;  // 6 blocks * 256 = 1536
  if (idx < 1024) {
    int s2 = idx >> 8, n = (idx >> 6) & 3, lane = idx & 63;
    int lo = lane & 15, hi = lane >> 4;
    ushort h[8];
#pragma unroll
    for (int j = 0; j < 8; j++) h[j] = f2b(Wm[(s2 * 32 + hi * 8 + j) * 64 + lo + 16 * n]);
    uint4 u;
    u.x = (uint)h[0] | ((uint)h[1] << 16); u.y = (uint)h[2] | ((uint)h[3] << 16);
    u.z = (uint)h[4] | ((uint)h[5] << 16); u.w = (uint)h[6] | ((uint)h[7] << 16);
    wmP[idx] = u;
  } else if (idx < 1536) {
    int k = idx - 1024;
    int s = k >> 8, n = (k >> 6) & 3, lane = k & 63;
    int lo = lane & 15, hi = lane >> 4;
    ushort h[8];
#pragma unroll
    for (int j = 0; j < 8; j++) h[j] = f2b(We[(s * 32 + hi * 8 + j) * 64 + lo + 16 * n]);
    uint4 u;
    u.x = (uint)h[0] | ((uint)h[1] << 16); u.y = (uint)h[2] | ((uint)h[3] << 16);
    u.z = (uint)h[4] | ((uint)h[5] << 16); u.w = (uint)h[6] | ((uint)h[7] << 16);
    weP[k] = u;
  }
}

// ---------- K1: xl = x@Wl, xr = x@Wr ----------
__global__ __launch_bounds__(256, 3) void k_node_linear(
    const float* __restrict__ x, const float* __restrict__ Wl,
    const float* __restrict__ Wr, float* __restrict__ xl,
    float* __restrict__ xr, int n) {
  int i = blockIdx.x * 256 + threadIdx.x;
  if (i >= n) return;
  const float4* px = (const float4*)(x + (size_t)i * 64);
  float accl[64], accr[64];
#pragma unroll
  for (int c = 0; c < 64; c++) { accl[c] = 0.f; accr[c] = 0.f; }
  for (int kq = 0; kq < 16; kq++) {
    float4 v = px[kq];
#pragma unroll
    for (int j = 0; j < 4; j++) {
      float xv = (j == 0) ? v.x : (j == 1) ? v.y : (j == 2) ? v.z : v.w;
      const float* wl = Wl + (kq * 4 + j) * 64;
      const float* wr = Wr + (kq * 4 + j) * 64;
#pragma unroll
      for (int c = 0; c < 64; c++) {
        accl[c] = fmaf(xv, wl[c], accl[c]);
        accr[c] = fmaf(xv, wr[c], accr[c]);
      }
    }
  }
  float4* pl = (float4*)(xl + (size_t)i * 64);
  float4* pr = (float4*)(xr + (size_t)i * 64);
#pragma unroll
  for (int q = 0; q < 16; q++) {
    float4 a, b;
    a.x = accl[4 * q]; a.y = accl[4 * q + 1]; a.z = accl[4 * q + 2]; a.w = accl[4 * q + 3];
    b.x = accr[4 * q]; b.y = accr[4 * q + 1]; b.z = accr[4 * q + 2]; b.w = accr[4 * q + 3];
    pl[q] = a; pr[q] = b;
  }
}

// ---------- K2: logits via MFMA, pipelined (swapped operands: D[col][edge]) ----------
template <bool PACKED>
__global__ __launch_bounds__(256) void k_edge_logits(
    const float* __restrict__ ea, const int* __restrict__ ei,
    const float* __restrict__ We, const float* __restrict__ att,
    const float* __restrict__ xl, const float* __restrict__ xr,
    const uint4* __restrict__ weP, float* __restrict__ logits,
    int* __restrict__ counts) {
  int tid = threadIdx.x;
  int w = tid >> 6, l = tid & 63;
  int lo16 = l & 15, hi4 = l >> 4;
  bf16x8 aw[4][2];
  if (PACKED) {
#pragma unroll
    for (int s = 0; s < 2; s++)
#pragma unroll
      for (int n = 0; n < 4; n++)
        aw[n][s] = __builtin_bit_cast(bf16x8, weP[(s * 4 + n) * 64 + l]);
  } else {
    for (int n = 0; n < 4; n++)
      for (int s = 0; s < 2; s++) {
        bf16x8 t;
#pragma unroll
        for (int j = 0; j < 8; j++)
          t[j] = (short)f2b(We[(s * 32 + hi4 * 8 + j) * 64 + lo16 + 16 * n]);
        aw[n][s] = t;
      }
  }
  float att4[4][4];
#pragma unroll
  for (int n = 0; n < 4; n++) {
    float4 a = *(const float4*)(att + 16 * n + hi4 * 4);
    att4[n][0] = a.x; att4[n][1] = a.y; att4[n][2] = a.z; att4[n][3] = a.w;
  }
  int wgid = blockIdx.x * 4 + w;
  int ebase = wgid * NT * 16;
  // prologue: tile-0 indices
  int sj = ei[ebase + lo16], dj = ei[EE + ebase + lo16];
  for (int it = 0; it < NT; it++) {
    int er = ebase + it * 16 + lo16;
    int djc = dj;
    // gathers for this tile issue NOW (indices arrived during prev tile)
    fx4 gl[4], gr[4];
#pragma unroll
    for (int n = 0; n < 4; n++) {
      gl[n] = *(const fx4*)(xl + (size_t)sj * 64 + 16 * n + hi4 * 4);
      gr[n] = *(const fx4*)(xr + (size_t)dj * 64 + 16 * n + hi4 * 4);
    }
    // prefetch next tile's indices (latency hidden by pack+MFMA below)
    if (it + 1 < NT) {
      sj = ei[er + 16];
      dj = ei[EE + er + 16];
    }
    // ea -> bf16 B-frags
    bf16x8 bfr[2];
#pragma unroll
    for (int s2 = 0; s2 < 2; s2++) {
      const fx4* p = (const fx4*)(ea + (size_t)er * 64 + s2 * 32 + hi4 * 8);
      fx4 f0 = p[0];
      fx4 f1 = p[1];
      uint4 u;
      u.x = pk2(f0[0], f0[1]); u.y = pk2(f0[2], f0[3]);
      u.z = pk2(f1[0], f1[1]); u.w = pk2(f1[2], f1[3]);
      bfr[s2] = __builtin_bit_cast(bf16x8, u);
    }
    f32x4 z4 = {0.f, 0.f, 0.f, 0.f};
    f32x4 acc[4] = {z4, z4, z4, z4};
#pragma unroll
    for (int s2 = 0; s2 < 2; s2++)
#pragma unroll
      for (int n = 0; n < 4; n++)
        acc[n] = __builtin_amdgcn_mfma_f32_16x16x32_bf16(aw[n][s2], bfr[s2], acc[n], 0, 0, 0);
    // D[m = We-col = hi4*4+r (+16n), n = edge = lo16]
    float lg[4];
#pragma unroll
    for (int n = 0; n < 4; n++) {
      float s = 0.f;
#pragma unroll
      for (int r = 0; r < 4; r++) {
        float z = acc[n][r] + gl[n][r] + gr[n][r];
        z = (z >= 0.f) ? z : 0.2f * z;
        s += z * att4[n][r];
      }
      s += __shfl_xor(s, 16, 64);
      s += __shfl_xor(s, 32, 64);
      lg[n] = s;
    }
    if (hi4 == 0) {
      fx4 o = {lg[0], lg[1], lg[2], lg[3]};
      ((fx4*)logits)[er] = o;
      atomicAdd(&counts[djc], 1);
    }
  }
}

// ---------- K3a/b/c: hierarchical exclusive scan of counts ----------
__global__ __launch_bounds__(256) void k_scan_sum(const int* __restrict__ counts,
                                                  int* __restrict__ bsum, int n) {
  __shared__ int red[256];
  int t = threadIdx.x;
  int idx = blockIdx.x * 256 + t;
  red[t] = (idx < n) ? counts[idx] : 0;
  __syncthreads();
  for (int off = 128; off > 0; off >>= 1) {
    if (t < off) red[t] += red[t + off];
    __syncthreads();
  }
  if (t == 0) bsum[blockIdx.x] = red[0];
}
__global__ __launch_bounds__(256) void k_scan_blk(const int* __restrict__ bsum,
                                                  int* __restrict__ boff,
                                                  int* __restrict__ offsets_end, int nb) {
  __shared__ int tmp[256];
  int t = threadIdx.x;
  int v = (t < nb) ? bsum[t] : 0;
  tmp[t] = v;
  __syncthreads();
  for (int off = 1; off < 256; off <<= 1) {
    int u = (t >= off) ? tmp[t - off] : 0;
    __syncthreads();
    tmp[t] += u;
    __syncthreads();
  }
  if (t < nb) boff[t] = tmp[t] - v;
  if (t == 255) offsets_end[0] = tmp[255];
}
__global__ __launch_bounds__(256) void k_scan_apply(const int* __restrict__ counts,
                                                    const int* __restrict__ boff,
                                                    int* __restrict__ offsets,
                                                    int* __restrict__ cursor, int n) {
  __shared__ int tmp[256];
  int t = threadIdx.x;
  int idx = blockIdx.x * 256 + t;
  int v = (idx < n) ? counts[idx] : 0;
  tmp[t] = v;
  __syncthreads();
  for (int off = 1; off < 256; off <<= 1) {
    int u = (t >= off) ? tmp[t - off] : 0;
    __syncthreads();
    tmp[t] += u;
    __syncthreads();
  }
  if (idx < n) {
    int ex = boff[blockIdx.x] + tmp[t] - v;
    offsets[idx] = ex;
    cursor[idx] = ex;
  }
}

// ---------- K4: scatter edge ids into CSR ----------
__global__ __launch_bounds__(256) void k_scatter(const int* __restrict__ ei,
                                                 int* __restrict__ cursor,
                                                 int* __restrict__ edge_of, int ne) {
  int e = blockIdx.x * blockDim.x + threadIdx.x;
  for (; e < ne; e += gridDim.x * blockDim.x) {
    int d = ei[EE + e];
    int pos = atomicAdd(&cursor[d], 1);
    edge_of[pos] = e;
  }
}

// ---------- K5: segment softmax + aggregate, lane-parallel edge meta ----------
__global__ __launch_bounds__(256) void k_node_agg(
    const int* __restrict__ ei, const int* __restrict__ offsets,
    const int* __restrict__ edge_of, const float* __restrict__ logits,
    const float* __restrict__ xl, const float* __restrict__ bias,
    float* __restrict__ xout, ushort* __restrict__ xb, int n) {
  int tid = threadIdx.x;
  int y = tid >> 6, l = tid & 63;
  int h = l >> 4;
  float bv = bias[l];
  const float NINF = -__builtin_inff();
  for (int base = blockIdx.x * 4; base < n; base += gridDim.x * 4) {
    int i = base + y;
    if (i >= n) continue;  // wave-uniform
    int beg = offsets[i], end = offsets[i + 1];
    float m = NINF, den = 0.f, acc = 0.f;
    for (int c0 = beg; c0 < end; c0 += 64) {
      int cnt = min(64, end - c0);
      // phase A: lane l <-> edge l of this chunk (parallel meta loads)
      int e_l = 0, s_l = 0;
      fx4 lg4 = {NINF, NINF, NINF, NINF};
      if (l < cnt) {
        e_l = edge_of[c0 + l];
        s_l = ei[e_l];
        lg4 = ((const fx4*)logits)[e_l];
      }
      // per-head max over chunk (wave reduce)
      float mh[4];
#pragma unroll
      for (int hh = 0; hh < 4; hh++) {
        float v = lg4[hh];
#pragma unroll
        for (int off = 32; off > 0; off >>= 1) v = fmaxf(v, __shfl_xor(v, off, 64));
        mh[hh] = v;
      }
      float mnew = fmaxf(m, mh[h]);
      float corr = __expf(m - mnew);   // 0 when m was -inf
      den *= corr; acc *= corr; m = mnew;
      // phase B: 4 edges per step; addresses via shfl (no memory round trip)
      for (int j = 0; j < cnt; j += 4) {
        int nb4 = min(4, cnt - j);
        float xv[4], lgv[4];
#pragma unroll
        for (int u = 0; u < 4; u++) {
          if (u < nb4) {
            int su = __shfl(s_l, j + u, 64);
            int eu = __shfl(e_l, j + u, 64);
            xv[u] = xl[(size_t)su * 64 + l];
            lgv[u] = logits[(size_t)eu * 4 + h];
          }
        }
#pragma unroll
        for (int u = 0; u < 4; u++) {
          if (u < nb4) {
            float p = __expf(lgv[u] - m);
            den += p;
            acc = fmaf(p, xv[u], acc);
          }
        }
      }
    }
    float o = acc / (den + 1e-16f) + bv;
    xout[(size_t)i * 64 + l] = o;
    if (xb) xb[(size_t)i * 64 + l] = f2b(o);
  }
}

// ---------- K6: edge MLP via MFMA, software-pipelined ----------
template <bool PACKED>
__global__ __launch_bounds__(256) void k_edge_mlp(
    const float* __restrict__ ea, const int* __restrict__ ei,
    const float* __restrict__ xoutf, const ushort* __restrict__ xb,
    const float* __restrict__ lng, const float* __restrict__ lnb,
    const float* __restrict__ Wm, const uint4* __restrict__ wmP,
    const float* __restrict__ bm, float* __restrict__ eout) {
  __shared__ float sT[4][16 * 68];   // per-wave transpose buffer
  int tid = threadIdx.x;
  int w = tid >> 6, l = tid & 63;
  int lo16 = l & 15, hi4 = l >> 4;
  bf16x8 bwm[4][4];
  if (PACKED) {
#pragma unroll
    for (int s2 = 0; s2 < 4; s2++)
#pragma unroll
      for (int n = 0; n < 4; n++)
        bwm[n][s2] = __builtin_bit_cast(bf16x8, wmP[(s2 * 4 + n) * 64 + l]);
  } else {
    for (int n = 0; n < 4; n++)
      for (int s2 = 0; s2 < 4; s2++) {
        bf16x8 t;
#pragma unroll
        for (int j = 0; j < 8; j++)
          t[j] = (short)f2b(Wm[(s2 * 32 + hi4 * 8 + j) * 64 + lo16 + 16 * n]);
        bwm[n][s2] = t;
      }
  }
  float bmv[4];
#pragma unroll
  for (int n = 0; n < 4; n++) bmv[n] = bm[lo16 + 16 * n];

  int wgid = blockIdx.x * 4 + w;
  int ebase = wgid * NT * 16;
  int m2 = l >> 2, q2 = l & 3;   // epilogue row/quarter

  // prologue: tile-0 indices + gathers
  int sj = ei[ebase + lo16], dj = ei[EE + ebase + lo16];
  uint4 pf0, pf1, pf2, pf3;
  if (PACKED) {
    pf0 = *(const uint4*)(xb + (size_t)sj * 64 + hi4 * 8);
    pf1 = *(const uint4*)(xb + (size_t)sj * 64 + 32 + hi4 * 8);
    pf2 = *(const uint4*)(xb + (size_t)dj * 64 + hi4 * 8);
    pf3 = *(const uint4*)(xb + (size_t)dj * 64 + 32 + hi4 * 8);
  }
  for (int it = 0; it < NT; it++) {
    int e0 = ebase + it * 16;
    // unpack current gathers
    float v[4][8];
    if (PACKED) {
      up8(pf0, v[0]); up8(pf1, v[1]); up8(pf2, v[2]); up8(pf3, v[3]);
    } else {
#pragma unroll
      for (int s2 = 0; s2 < 4; s2++) {
        const float* src = (s2 < 2) ? (xoutf + (size_t)sj * 64 + (s2 & 1) * 32 + hi4 * 8)
                                    : (xoutf + (size_t)dj * 64 + (s2 & 1) * 32 + hi4 * 8);
        float4 a = *(const float4*)src;
        float4 b = *(const float4*)(src + 4);
        v[s2][0] = a.x; v[s2][1] = a.y; v[s2][2] = a.z; v[s2][3] = a.w;
        v[s2][4] = b.x; v[s2][5] = b.y; v[s2][6] = b.z; v[s2][7] = b.w;
      }
    }
    // prefetch next tile's indices (hidden under LN+MFMA)
    int sjn = 0, djn = 0;
    if (it + 1 < NT) {
      sjn = ei[e0 + 16 + lo16];
      djn = ei[EE + e0 + 16 + lo16];
    }
    // LN stats (quad-reduce across hi4 groups)
    float sm = 0.f, sq = 0.f;
#pragma unroll
    for (int s2 = 0; s2 < 4; s2++)
#pragma unroll
      for (int j = 0; j < 8; j++) { sm += v[s2][j]; sq += v[s2][j] * v[s2][j]; }
    sm += __shfl_xor(sm, 16, 64); sm += __shfl_xor(sm, 32, 64);
    sq += __shfl_xor(sq, 16, 64); sq += __shfl_xor(sq, 32, 64);
    float mean = sm * (1.f / 128.f);
    float var = sq * (1.f / 128.f) - mean * mean;
    float rs = rsqrtf(var + 1e-5f);
    // normalize -> bf16 A-frags -> MFMA
    f32x4 acc[4];
#pragma unroll
    for (int n = 0; n < 4; n++) {
      f32x4 c = {bmv[n], bmv[n], bmv[n], bmv[n]};
      acc[n] = c;
    }
#pragma unroll
    for (int s2 = 0; s2 < 4; s2++) {
      float4 ga = *(const float4*)(lng + s2 * 32 + hi4 * 8);
      float4 gb = *(const float4*)(lng + s2 * 32 + hi4 * 8 + 4);
      float4 ba = *(const float4*)(lnb + s2 * 32 + hi4 * 8);
      float4 bb = *(const float4*)(lnb + s2 * 32 + hi4 * 8 + 4);
      float g8[8] = {ga.x, ga.y, ga.z, ga.w, gb.x, gb.y, gb.z, gb.w};
      float b8[8] = {ba.x, ba.y, ba.z, ba.w, bb.x, bb.y, bb.z, bb.w};
      float h8[8];
#pragma unroll
      for (int j = 0; j < 8; j++)
        h8[j] = fmaxf(fmaf((v[s2][j] - mean) * rs, g8[j], b8[j]), 0.f);
      uint4 u;
      u.x = pk2(h8[0], h8[1]); u.y = pk2(h8[2], h8[3]);
      u.z = pk2(h8[4], h8[5]); u.w = pk2(h8[6], h8[7]);
      bf16x8 afr = __builtin_bit_cast(bf16x8, u);
#pragma unroll
      for (int n = 0; n < 4; n++)
        acc[n] = __builtin_amdgcn_mfma_f32_16x16x32_bf16(afr, bwm[n][s2], acc[n], 0, 0, 0);
    }
    // issue next tile's gathers (overlap with epilogue's HBM traffic)
    if (it + 1 < NT) {
      if (PACKED) {
        pf0 = *(const uint4*)(xb + (size_t)sjn * 64 + hi4 * 8);
        pf1 = *(const uint4*)(xb + (size_t)sjn * 64 + 32 + hi4 * 8);
        pf2 = *(const uint4*)(xb + (size_t)djn * 64 + hi4 * 8);
        pf3 = *(const uint4*)(xb + (size_t)djn * 64 + 32 + hi4 * 8);
      }
      sj = sjn; dj = djn;
    }
    // transpose via wave-local LDS: D[row = hi4*4+r (edge), col = lo16+16n]
#pragma unroll
    for (int n = 0; n < 4; n++)
#pragma unroll
      for (int r = 0; r < 4; r++)
        sT[w][(hi4 * 4 + r) * 68 + lo16 + 16 * n] = acc[n][r];
    // epilogue: coalesced ea-read + eout-write (L2 write-combines)
#pragma unroll
    for (int c = 0; c < 4; c++) {
      fx4 t4 = *(const fx4*)&sT[w][m2 * 68 + q2 * 16 + 4 * c];
      size_t off = (size_t)(e0 + m2) * 64 + q2 * 16 + 4 * c;
      fx4 r4 = *(const fx4*)(ea + off);
      fx4 o = r4 + t4;
      *(fx4*)(eout + off) = o;
    }
  }
}

extern "C" void kernel_launch(void* const* d_in, const int* in_sizes, int n_in,
                              void* d_out, int out_size, void* d_ws, size_t ws_size,
                              hipStream_t stream) {
  const float* x   = (const float*)d_in[0];
  const int*   ei  = (const int*)d_in[1];
  const float* ea  = (const float*)d_in[2];
  const float* Wl  = (const float*)d_in[3];
  const float* Wr  = (const float*)d_in[4];
  const float* We  = (const float*)d_in[5];
  const float* att = (const float*)d_in[6];
  const float* cb  = (const float*)d_in[7];
  const float* lng = (const float*)d_in[8];
  const float* lnb = (const float*)d_in[9];
  const float* Wm  = (const float*)d_in[10];
  const float* bm  = (const float*)d_in[11];

  float* out  = (float*)d_out;
  float* xout = out;                       // [N,64]
  float* eout = out + (size_t)NN * 64;     // [E,64]

  const int nb = (NN + 255) / 256;         // 196 scan blocks

  size_t packBytes = (size_t)(1024 + 512) * 16;                    // wmP + weP
  size_t fWords    = (size_t)NN * 64 * 2 + (size_t)EE * 4;         // xl, xr, logits
  size_t xbWords   = (size_t)NN * 64 / 2;                          // bf16 x_out
  size_t intWords  = (size_t)NN * 3 + 1 + (size_t)EE + 512;
  size_t needBytes = packBytes + (fWords + xbWords + intWords) * 4;
  bool useWs = (ws_size >= needBytes);

  uint4*  wmP = useWs ? (uint4*)d_ws : nullptr;
  uint4*  weP = useWs ? wmP + 1024 : nullptr;
  float*  fbase = useWs ? (float*)((char*)d_ws + packBytes) : eout;

  float*  xl      = fbase;
  float*  xr      = xl + (size_t)NN * 64;
  float*  logits  = xr + (size_t)NN * 64;
  ushort* xb      = useWs ? (ushort*)(logits + (size_t)EE * 4) : nullptr;
  int*    counts  = useWs ? (int*)(xb + (size_t)NN * 64)
                          : (int*)(logits + (size_t)EE * 4);
  int*    offsets = counts + NN;
  int*    cursor  = offsets + NN + 1;
  int*    edge_of = cursor + NN;
  int*    bsum    = edge_of + EE;
  int*    boff    = bsum + 256;

  hipMemsetAsync(counts, 0, NN * sizeof(int), stream);
  if (useWs) k_prep<<<6, 256, 0, stream>>>(Wm, We, wmP, weP);
  k_node_linear<<<(NN + 255) / 256, 256, 0, stream>>>(x, Wl, Wr, xl, xr, NN);
  if (useWs)
    k_edge_logits<true><<<2500, 256, 0, stream>>>(ea, ei, We, att, xl, xr, weP, logits, counts);
  else
    k_edge_logits<false><<<2500, 256, 0, stream>>>(ea, ei, We, att, xl, xr, nullptr, logits, counts);
  k_scan_sum<<<nb, 256, 0, stream>>>(counts, bsum, NN);
  k_scan_blk<<<1, 256, 0, stream>>>(bsum, boff, offsets + NN, nb);
  k_scan_apply<<<nb, 256, 0, stream>>>(counts, boff, offsets, cursor, NN);
  k_scatter<<<1024, 256, 0, stream>>>(ei, cursor, edge_of, EE);
  k_node_agg<<<2048, 256, 0, stream>>>(ei, offsets, edge_of, logits, xl, cb, xout, xb, NN);
  if (useWs)
    k_edge_mlp<true><<<2500, 256, 0, stream>>>(ea, ei, xout, xb, lng, lnb, Wm, wmP, bm, eout);
  else
    k_edge_mlp<false><<<2500, 256, 0, stream>>>(ea, ei, xout, nullptr, lng, lnb, Wm, nullptr, bm, eout);
}